// Round 9
// baseline (290.095 us; speedup 1.0000x reference)
//
#include <hip/hip_runtime.h>
#include <stdint.h>

#define S_LEN 8192
#define DIM   1024
#define NH    16
#define HD    64
#define WIN   1024
#define GTOK  256
#define QKV_STRIDE (3 * DIM)

typedef __attribute__((ext_vector_type(8))) short bf16x8;
typedef __attribute__((ext_vector_type(4))) float f32x4;
typedef __attribute__((ext_vector_type(16))) float f32x16;
typedef unsigned short u16;
typedef uint32_t u32;

__device__ __forceinline__ u16 f2bf(float f) {
  union { float f; uint32_t u; } v; v.f = f;
  uint32_t r = v.u + 0x7fffu + ((v.u >> 16) & 1u);
  return (u16)(r >> 16);
}
__device__ __forceinline__ float bf2f(u16 b) {
  union { uint32_t u; float f; } v; v.u = ((uint32_t)b) << 16;
  return v.f;
}
__device__ __forceinline__ uint32_t cvtpk(float a, float b) {
  uint32_t r;
  asm("v_cvt_pk_bf16_f32 %0, %1, %2" : "=v"(r) : "v"(a), "v"(b));
  return r;
}

__device__ __forceinline__ void gload_lds16(const void* g, void* l) {
  __builtin_amdgcn_global_load_lds((const __attribute__((address_space(1))) void*)g,
                                   (__attribute__((address_space(3))) void*)l, 16, 0, 0);
}

// ---------------- RMSNorm + scorer ----------------
__global__ __launch_bounds__(256) void rmsnorm_score_kernel(
    const float* __restrict__ x, const float* __restrict__ nw,
    const float* __restrict__ sw, const float* __restrict__ sb,
    u16* __restrict__ h, float* __restrict__ scores) {
  int row = blockIdx.x, tid = threadIdx.x;
  const float4* xr = (const float4*)(x + (size_t)row * DIM);
  float4 v = xr[tid];
  float ss = v.x * v.x + v.y * v.y + v.z * v.z + v.w * v.w;
#pragma unroll
  for (int o = 32; o >= 1; o >>= 1) ss += __shfl_xor(ss, o);
  __shared__ float red[4], red2[4];
  int wv = tid >> 6;
  if ((tid & 63) == 0) red[wv] = ss;
  __syncthreads();
  ss = red[0] + red[1] + red[2] + red[3];
  float rn = rsqrtf(ss * (1.0f / DIM) + 1e-6f);
  float4 w4 = ((const float4*)nw)[tid];
  float h0 = v.x * rn * w4.x, h1 = v.y * rn * w4.y;
  float h2 = v.z * rn * w4.z, h3 = v.w * rn * w4.w;
  uint64_t pack = (uint64_t)f2bf(h0) | ((uint64_t)f2bf(h1) << 16) |
                  ((uint64_t)f2bf(h2) << 32) | ((uint64_t)f2bf(h3) << 48);
  *(uint64_t*)(h + (size_t)row * DIM + tid * 4) = pack;
  float4 s4 = ((const float4*)sw)[tid];
  float sc = h0 * s4.x + h1 * s4.y + h2 * s4.z + h3 * s4.w;
#pragma unroll
  for (int o = 32; o >= 1; o >>= 1) sc += __shfl_xor(sc, o);
  if ((tid & 63) == 0) red2[wv] = sc;
  __syncthreads();
  if (tid == 0) scores[row] = red2[0] + red2[1] + red2[2] + red2[3] + sb[0];
}

// ---------------- weight transpose + bf16 convert ----------------
__global__ __launch_bounds__(256) void transpose_w_kernel(
    const float* __restrict__ wq, const float* __restrict__ wk,
    const float* __restrict__ wv, const float* __restrict__ wo,
    u16* __restrict__ wqkvT, u16* __restrict__ woutT) {
  __shared__ float tile[32][33];
  int z = blockIdx.z;
  const float* src = (z == 0) ? wq : (z == 1) ? wk : (z == 2) ? wv : wo;
  u16* dst = (z < 3) ? (wqkvT + (size_t)z * DIM * DIM) : woutT;
  int tx = threadIdx.x, ty = threadIdx.y;  // 32 x 8
  int n0 = blockIdx.x * 32, k0 = blockIdx.y * 32;
#pragma unroll
  for (int i = 0; i < 4; i++)
    tile[ty + i * 8][tx] = src[(size_t)(k0 + ty + i * 8) * DIM + n0 + tx];
  __syncthreads();
#pragma unroll
  for (int i = 0; i < 4; i++)
    dst[(size_t)(n0 + ty + i * 8) * DIM + k0 + tx] = f2bf(tile[tx][ty + i * 8]);
}

// ---------------- exact top-G by distributed rank counting ----------------
__global__ __launch_bounds__(256) void zero_kernel(int* __restrict__ p) {
  p[blockIdx.x * 256 + threadIdx.x] = 0;
}

__global__ __launch_bounds__(256) void topk_count_kernel(
    const float* __restrict__ scores, int* __restrict__ cnt) {
  __shared__ float sj[1024];
  int jbase = blockIdx.y * 1024;
  for (int t = threadIdx.x; t < 1024; t += 256) sj[t] = scores[jbase + t];
  __syncthreads();
  int i = blockIdx.x * 256 + threadIdx.x;
  float my = scores[i];
  int c = 0;
  const float4* s4 = (const float4*)sj;
#pragma unroll 4
  for (int j = 0; j < 256; j++) {
    float4 v = s4[j];
    int b = jbase + j * 4;
    c += (v.x > my) || (v.x == my && (b + 0) < i);
    c += (v.y > my) || (v.y == my && (b + 1) < i);
    c += (v.z > my) || (v.z == my && (b + 2) < i);
    c += (v.w > my) || (v.w == my && (b + 3) < i);
  }
  if (c) atomicAdd(&cnt[i], c);
}

// rank among SELECTED tokens by token index -> sorted-by-position top-G
__global__ __launch_bounds__(256) void selrank_kernel(
    const int* __restrict__ cnt, int* __restrict__ scnt) {
  __shared__ int sj[1024];
  int jbase = blockIdx.y * 1024;
  for (int t = threadIdx.x; t < 1024; t += 256) sj[t] = (cnt[jbase + t] < GTOK);
  __syncthreads();
  int i = blockIdx.x * 256 + threadIdx.x;
  if (cnt[i] >= GTOK) return;
  int c = 0;
  const int4* s4 = (const int4*)sj;
#pragma unroll 4
  for (int j = 0; j < 256; j++) {
    int4 v = s4[j];
    int b = jbase + j * 4;
    c += (v.x && (b + 0) < i) + (v.y && (b + 1) < i) +
         (v.z && (b + 2) < i) + (v.w && (b + 3) < i);
  }
  if (c) atomicAdd(&scnt[i], c);
}

__global__ __launch_bounds__(256) void selscatter_kernel(
    const int* __restrict__ cnt, const int* __restrict__ scnt, int* __restrict__ gidxS) {
  int i = blockIdx.x * 256 + threadIdx.x;
  if (cnt[i] < GTOK) gidxS[scnt[i]] = i;
}

// ---------------- gather top-G K/V rows (sorted order) ----------------
__global__ __launch_bounds__(128) void gather_kernel(
    const u16* __restrict__ qkv, const int* __restrict__ gidx,
    u16* __restrict__ kg, u16* __restrict__ vg) {
  int g = blockIdx.x, t = threadIdx.x;
  size_t src = (size_t)gidx[g] * QKV_STRIDE;
  *(bf16x8*)(kg + (size_t)g * DIM + t * 8) = *(const bf16x8*)(qkv + src + DIM + t * 8);
  *(bf16x8*)(vg + (size_t)g * DIM + t * 8) = *(const bf16x8*)(qkv + src + 2 * DIM + t * 8);
}

// ---------------- GEMM 256Mx128N tile, 8 waves, BK=64, 3-buf 2-deep counted-vmcnt ----------------
// XCD-aware block swizzle (T1): each XCD gets a contiguous chunk -> B panel L2-resident.
template <int RESID>
__global__ __launch_bounds__(512, 2) void gemm256_kernel(
    const u16* __restrict__ A, const u16* __restrict__ B,
    u16* __restrict__ Cb, float* __restrict__ Cf, const float* __restrict__ X,
    int M, int N, int K) {
  __shared__ __align__(16) u16 As[3][256 * 64];
  __shared__ __align__(16) u16 Bs[3][128 * 64];
  const int tid = threadIdx.x;
  const int wave = tid >> 6, lane = tid & 63;
  const int l15 = lane & 15, l4 = lane >> 4;
  const int wr = wave >> 1, wc = wave & 1;  // 4M x 2N wave grid, 64x64 per wave
  // XCD swizzle: linear dispatch id -> chunked work id (nwg % 8 == 0 for both grids)
  const int nwg = gridDim.x * gridDim.y;
  const int l = blockIdx.x + (blockIdx.y << 5);     // gridDim.x == 32
  const int sw = (l & 7) * (nwg >> 3) + (l >> 3);
  const int mbase = (sw & 31) * 256, nbase = (sw >> 5) * 128;
  const int srow = lane >> 3, schunk = lane & 7;
  const int gcol = (schunk ^ srow) * 8;

  auto stage = [&](int tt, int b) {
    const int kt = tt << 6;
#pragma unroll
    for (int q = 0; q < 4; q++) {
      int row = wave * 32 + q * 8;
      gload_lds16(A + (size_t)(mbase + row + srow) * K + kt + gcol, &As[b][row * 64]);
    }
#pragma unroll
    for (int q = 0; q < 2; q++) {
      int row = wave * 16 + q * 8;
      gload_lds16(B + (size_t)(nbase + row + srow) * K + kt + gcol, &Bs[b][row * 64]);
    }
  };

  const int nt = K >> 6;
  f32x4 acc[4][4] = {};

  stage(0, 0);
  stage(1, 1);
  asm volatile("s_waitcnt vmcnt(6)" ::: "memory");
  __builtin_amdgcn_s_barrier();
  __builtin_amdgcn_sched_barrier(0);

  int cur = 0;
  for (int t = 0; t < nt; t++) {
    int pre = cur + 2; if (pre >= 3) pre -= 3;
    if (t + 2 < nt) stage(t + 2, pre);
    const u16* Ab = &As[cur][0];
    const u16* Bb = &Bs[cur][0];
    bf16x8 bfr[4][2], af[4][2];
#pragma unroll
    for (int nf = 0; nf < 4; nf++) {
      int row = wc * 64 + nf * 16 + l15;
#pragma unroll
      for (int kk = 0; kk < 2; kk++)
        bfr[nf][kk] = *(const bf16x8*)(Bb + row * 64 + (((kk * 4 + l4) ^ (l15 & 7)) * 8));
    }
#pragma unroll
    for (int mi = 0; mi < 4; mi++) {
      int row = wr * 64 + mi * 16 + l15;
#pragma unroll
      for (int kk = 0; kk < 2; kk++)
        af[mi][kk] = *(const bf16x8*)(Ab + row * 64 + (((kk * 4 + l4) ^ (l15 & 7)) * 8));
    }
    __builtin_amdgcn_s_setprio(1);
#pragma unroll
    for (int mi = 0; mi < 4; mi++)
#pragma unroll
      for (int nf = 0; nf < 4; nf++)
#pragma unroll
        for (int kk = 0; kk < 2; kk++)
          acc[mi][nf] = __builtin_amdgcn_mfma_f32_16x16x32_bf16(af[mi][kk], bfr[nf][kk],
                                                                acc[mi][nf], 0, 0, 0);
    __builtin_amdgcn_s_setprio(0);
    if (t + 1 < nt) {
      if (t + 2 < nt) asm volatile("s_waitcnt vmcnt(6)" ::: "memory");
      else            asm volatile("s_waitcnt vmcnt(0)" ::: "memory");
      __builtin_amdgcn_s_barrier();
      __builtin_amdgcn_sched_barrier(0);
    }
    cur = (cur + 1 == 3) ? 0 : cur + 1;
  }

#pragma unroll
  for (int mi = 0; mi < 4; mi++) {
#pragma unroll
    for (int nf = 0; nf < 4; nf++) {
#pragma unroll
      for (int r = 0; r < 4; r++) {
        int row = mbase + wr * 64 + mi * 16 + l4 * 4 + r;
        int col = nbase + wc * 64 + nf * 16 + l15;
        float v = acc[mi][nf][r];
        if (RESID) Cf[(size_t)row * N + col] = X[(size_t)row * N + col] + v;
        else       Cb[(size_t)row * N + col] = f2bf(v);
      }
    }
  }
}

// ---------------- fused flash attention v7: sorted-global suffix skip ----------------
// 8 waves, one 256-q supertile/block, 512 blocks. gidx sorted by position =>
// valid global tiles form a prefix: block shrinks nTiles by gcount; waves skip
// tiles whose min gpos exceeds their qwmax. launch_bounds(512,4) targets
// 2 blocks/CU. Raw lgkmcnt-only barrier keeps prefetch loads in flight.
__global__ __launch_bounds__(512, 4) void attn_kernel(
    const u16* __restrict__ qkv, const u16* __restrict__ kg,
    const u16* __restrict__ vg, const int* __restrict__ gidx,
    u16* __restrict__ o) {
  __shared__ __align__(16) u16 kT[2][64][72];   // [buf][key][d] (+8 pad)
  __shared__ __align__(16) u16 vT[2][64][72];   // [buf][d][key^((d>>4)<<4)]
  __shared__ int gposLds[2][64];
  const int tid = threadIdx.x, wave = tid >> 6, lane = tid & 63;
  const int l31 = lane & 31, hi = lane >> 5;

  // work-balanced (head, window, supertile) from dispatch rank
  const int r = blockIdx.x + 32 * blockIdx.y;   // [0,512)
  const int half = r >> 8, rr = r & 255;
  const int h = rr >> 4, w8 = rr & 7, jj = (rr >> 3) & 1;
  const int j = half ? (jj ? 1 : 0) : (jj ? 2 : 3);
  const int wbase = w8 * WIN;
  const int hoff = h * HD;
  const int qsbase = wbase + j * 256;
  const int nLocal = (j + 1) * 4;
  const int qsmax = qsbase + 255;
  // suffix skip: gidx sorted ascending -> valid global tiles are a prefix
  int gcount = 0;
#pragma unroll
  for (int g = 0; g < 4; g++) gcount += (gidx[g * 64] <= qsmax) ? 1 : 0;
  const int nTiles = nLocal + gcount;
  const int qrow = qsbase + wave * 32 + l31;
  const int qwmax = qsbase + wave * 32 + 31;

  // staging map: thread covers key=skey, dims sd8..sd8+7
  const int skey = tid >> 3, sd8 = (tid & 7) * 8;
  const int vcol = skey ^ ((sd8 >> 4) << 4);

  // Q B-fragments with scale*log2e folded in
  bf16x8 qf[4];
  {
    const float SC2 = 0.125f * 1.44269504088896f;
    const u16* qptr = qkv + (size_t)qrow * QKV_STRIDE + hoff + hi * 8;
#pragma unroll
    for (int ks = 0; ks < 4; ks++) {
      bf16x8 raw = *(const bf16x8*)(qptr + ks * 16);
      bf16x8 sc;
#pragma unroll
      for (int t = 0; t < 8; t++) sc[t] = (short)f2bf(bf2f((u16)raw[t]) * SC2);
      qf[ks] = sc;
    }
  }

  // prologue prefetch: window tile 0
  bf16x8 nk, nv;
  int ng = 0;
  {
    const u16* base = qkv + (size_t)(wbase + skey) * QKV_STRIDE + hoff + sd8;
    nk = *(const bf16x8*)(base + DIM);
    nv = *(const bf16x8*)(base + 2 * DIM);
  }

  f32x16 acc0 = {}, acc1 = {};
  float mr = -3.0e38f, lr = 0.f;

  for (int t = 0; t < nTiles; t++) {
    const int p = t & 1;
    const bool isLocal = (t < nLocal);
    const int tbase = wbase + t * 64;
    // ---- stage K (row-major) + V^T (swizzled) + gpos from prefetch regs ----
    *(bf16x8*)(&kT[p][skey][sd8]) = nk;
#pragma unroll
    for (int t8 = 0; t8 < 8; t8++) vT[p][sd8 + t8][vcol] = (u16)nv[t8];
    if (!isLocal && tid < 64) gposLds[p][tid] = ng;
    // ---- prefetch tile t+1 (loads stay in flight across the barrier) ----
    {
      const int nt = t + 1;
      const u16 *ksrc = nullptr, *vsrc = nullptr;
      if (nt < nLocal) {
        const u16* base = qkv + (size_t)(wbase + nt * 64 + skey) * QKV_STRIDE + hoff + sd8;
        ksrc = base + DIM; vsrc = base + 2 * DIM;
      } else if (nt < nTiles) {
        size_t grow = (size_t)((nt - nLocal) * 64 + skey) * DIM + hoff + sd8;
        ksrc = kg + grow; vsrc = vg + grow;
        if (tid < 64) ng = gidx[(nt - nLocal) * 64 + tid];
      }
      if (ksrc) { nk = *(const bf16x8*)(ksrc); nv = *(const bf16x8*)(vsrc); }
    }
    // ---- LDS fence + barrier WITHOUT vmcnt drain ----
    asm volatile("s_waitcnt lgkmcnt(0)" ::: "memory");
    __builtin_amdgcn_s_barrier();
    __builtin_amdgcn_sched_barrier(0);

    // fully-masked tile for this wave -> skip compute
    if (isLocal) {
      if (tbase > qwmax) continue;
    } else {
      if (gposLds[p][0] > qwmax) continue;  // sorted: [0] is the tile minimum
    }

    // ---- QK^T (swapped): S^T[key][q], K from LDS ----
    float sv[32];
    __builtin_amdgcn_s_setprio(1);
#pragma unroll
    for (int kb = 0; kb < 2; kb++) {
      const u16* krow = &kT[p][kb * 32 + l31][hi * 8];
      bf16x8 k0 = *(const bf16x8*)(krow);
      bf16x8 k1 = *(const bf16x8*)(krow + 16);
      bf16x8 k2 = *(const bf16x8*)(krow + 32);
      bf16x8 k3 = *(const bf16x8*)(krow + 48);
      f32x16 z = {};
      z = __builtin_amdgcn_mfma_f32_32x32x16_bf16(k0, qf[0], z, 0, 0, 0);
      z = __builtin_amdgcn_mfma_f32_32x32x16_bf16(k1, qf[1], z, 0, 0, 0);
      z = __builtin_amdgcn_mfma_f32_32x32x16_bf16(k2, qf[2], z, 0, 0, 0);
      z = __builtin_amdgcn_mfma_f32_32x32x16_bf16(k3, qf[3], z, 0, 0, 0);
#pragma unroll
      for (int rg = 0; rg < 16; rg++) sv[kb * 16 + rg] = z[rg];
    }
    __builtin_amdgcn_s_setprio(0);

    // ---- causal mask (scale folded into Q) ----
    if (isLocal) {
      const int lim = qrow - tbase;
      if (lim < 63) {
#pragma unroll
        for (int kb = 0; kb < 2; kb++)
#pragma unroll
          for (int rg = 0; rg < 16; rg++) {
            int crow = kb * 32 + (rg & 3) + 8 * (rg >> 2) + 4 * hi;
            if (crow > lim) sv[kb * 16 + rg] = -3.0e38f;
          }
      }
    } else {
#pragma unroll
      for (int kb = 0; kb < 2; kb++)
#pragma unroll
        for (int rg = 0; rg < 16; rg++) {
          int kpos = gposLds[p][kb * 32 + (rg & 3) + 8 * (rg >> 2) + 4 * hi];
          if (kpos > qrow) sv[kb * 16 + rg] = -3.0e38f;
        }
    }

    // ---- lane-local online softmax with defer-max ----
    float m0 = sv[0], m1 = sv[1], m2 = sv[2], m3 = sv[3];
#pragma unroll
    for (int i = 4; i < 32; i += 4) {
      m0 = fmaxf(m0, sv[i]);     m1 = fmaxf(m1, sv[i + 1]);
      m2 = fmaxf(m2, sv[i + 2]); m3 = fmaxf(m3, sv[i + 3]);
    }
    float vmax = fmaxf(fmaxf(m0, m1), fmaxf(m2, m3));
    vmax = fmaxf(vmax, __shfl_xor(vmax, 32));
    if (__any(vmax > mr + 11.0f)) {
      float mn = fmaxf(mr, vmax);
      float al = exp2f(mr - mn);
      lr *= al;
      mr = mn;
#pragma unroll
      for (int i = 0; i < 16; i++) { acc0[i] *= al; acc1[i] *= al; }
    }
    float s0 = 0.f, s1 = 0.f, s2 = 0.f, s3 = 0.f;
#pragma unroll
    for (int i = 0; i < 32; i += 4) {
      float p0 = exp2f(sv[i] - mr),     p1 = exp2f(sv[i + 1] - mr);
      float p2 = exp2f(sv[i + 2] - mr), p3 = exp2f(sv[i + 3] - mr);
      sv[i] = p0; sv[i + 1] = p1; sv[i + 2] = p2; sv[i + 3] = p3;
      s0 += p0; s1 += p1; s2 += p2; s3 += p3;
    }
    float ps = (s0 + s1) + (s2 + s3);
    ps += __shfl_xor(ps, 32);
    lr += ps;

    // ---- build P B-fragments in-register (cvt_pk + half-swap with lane^32) ----
    bf16x8 pf[4];
#pragma unroll
    for (int q4 = 0; q4 < 4; q4++) {
      int b = q4 * 8;
      uint32_t w0 = cvtpk(sv[b + 0], sv[b + 1]);
      uint32_t w1 = cvtpk(sv[b + 2], sv[b + 3]);
      uint32_t w2 = cvtpk(sv[b + 4], sv[b + 5]);
      uint32_t w3 = cvtpk(sv[b + 6], sv[b + 7]);
      uint32_t w0s = __shfl_xor((int)w0, 32), w2s = __shfl_xor((int)w2, 32);
      uint32_t w1s = __shfl_xor((int)w1, 32), w3s = __shfl_xor((int)w3, 32);
      union { uint32_t w[4]; bf16x8 v; } u;
      u.w[0] = hi ? w2s : w0;
      u.w[1] = hi ? w3s : w1;
      u.w[2] = hi ? w2 : w0s;
      u.w[3] = hi ? w3 : w1s;
      pf[q4] = u.v;
    }

    // ---- PV: O^T[d][q] = mfma(V^T, P) ----
    __builtin_amdgcn_s_setprio(1);
#pragma unroll
    for (int dblk = 0; dblk < 2; dblk++) {
      const int swz = (dblk * 2 + (l31 >> 4)) << 4;
      const u16* vrow = &vT[p][dblk * 32 + l31][0];
      f32x16 a = dblk ? acc1 : acc0;
#pragma unroll
      for (int ksg = 0; ksg < 4; ksg++) {
        bf16x8 vf = *(const bf16x8*)(vrow + ((ksg * 16 + hi * 8) ^ swz));
        a = __builtin_amdgcn_mfma_f32_32x32x16_bf16(vf, pf[ksg], a, 0, 0, 0);
      }
      if (dblk) acc1 = a; else acc0 = a;
    }
    __builtin_amdgcn_s_setprio(0);
  }

  // ---- normalize (lane-local) + store O ----
  float inv = 1.0f / lr;
#pragma unroll
  for (int dblk = 0; dblk < 2; dblk++) {
    f32x16 a = dblk ? acc1 : acc0;
#pragma unroll
    for (int g = 0; g < 4; g++) {
      uint64_t pk = (uint64_t)f2bf(a[g * 4 + 0] * inv)
                  | ((uint64_t)f2bf(a[g * 4 + 1] * inv) << 16)
                  | ((uint64_t)f2bf(a[g * 4 + 2] * inv) << 32)
                  | ((uint64_t)f2bf(a[g * 4 + 3] * inv) << 48);
      *(uint64_t*)(o + (size_t)qrow * DIM + hoff + dblk * 32 + g * 8 + 4 * hi) = pk;
    }
  }
}

// ---------------- launch ----------------
extern "C" void kernel_launch(void* const* d_in, const int* in_sizes, int n_in,
                              void* d_out, int out_size, void* d_ws, size_t ws_size,
                              hipStream_t stream) {
  const float* x  = (const float*)d_in[0];
  const float* nw = (const float*)d_in[1];
  const float* wq = (const float*)d_in[2];
  const float* wk = (const float*)d_in[3];
  const float* wv = (const float*)d_in[4];
  const float* wo = (const float*)d_in[5];
  const float* sw = (const float*)d_in[6];
  const float* sb = (const float*)d_in[7];
  float* out = (float*)d_out;

  char* ws = (char*)d_ws;
  size_t off = 0;
  auto alloc = [&](size_t b) {
    char* p = ws + off;
    off = (off + b + 255) & ~(size_t)255;
    return p;
  };
  u16*   h      = (u16*)alloc((size_t)S_LEN * DIM * 2);
  u16*   wqkvT  = (u16*)alloc((size_t)3 * DIM * DIM * 2);
  u16*   woutT  = (u16*)alloc((size_t)DIM * DIM * 2);
  u16*   qkv    = (u16*)alloc((size_t)S_LEN * 3 * DIM * 2);
  u16*   obuf   = (u16*)alloc((size_t)S_LEN * DIM * 2);
  float* scores = (float*)alloc((size_t)S_LEN * 4);
  int*   cnt    = (int*)alloc((size_t)S_LEN * 4);
  int*   scnt   = (int*)alloc((size_t)S_LEN * 4);
  int*   gidxS  = (int*)alloc((size_t)GTOK * 4);
  u16*   kgbuf  = (u16*)alloc((size_t)GTOK * DIM * 2);
  u16*   vgbuf  = (u16*)alloc((size_t)GTOK * DIM * 2);

  transpose_w_kernel<<<dim3(32, 32, 4), dim3(32, 8), 0, stream>>>(wq, wk, wv, wo, wqkvT, woutT);
  rmsnorm_score_kernel<<<dim3(S_LEN), dim3(256), 0, stream>>>(x, nw, sw, sb, h, scores);
  zero_kernel<<<dim3(S_LEN / 256), dim3(256), 0, stream>>>(cnt);
  zero_kernel<<<dim3(S_LEN / 256), dim3(256), 0, stream>>>(scnt);
  topk_count_kernel<<<dim3(32, 8), dim3(256), 0, stream>>>(scores, cnt);
  selrank_kernel<<<dim3(32, 8), dim3(256), 0, stream>>>(cnt, scnt);
  selscatter_kernel<<<dim3(S_LEN / 256), dim3(256), 0, stream>>>(cnt, scnt, gidxS);
  gemm256_kernel<0><<<dim3(32, 24), dim3(512), 0, stream>>>(h, wqkvT, qkv, nullptr, nullptr,
                                                            S_LEN, 3 * DIM, DIM);
  gather_kernel<<<dim3(GTOK), dim3(128), 0, stream>>>(qkv, gidxS, kgbuf, vgbuf);
  attn_kernel<<<dim3(32, NH), dim3(512), 0, stream>>>(qkv, kgbuf, vgbuf, gidxS, obuf);
  gemm256_kernel<1><<<dim3(32, 8), dim3(512), 0, stream>>>(obuf, woutT, nullptr, out, x,
                                                           S_LEN, DIM, DIM);
}

// Round 10
// 263.931 us; speedup vs baseline: 1.0991x; 1.0991x over previous
//
#include <hip/hip_runtime.h>
#include <stdint.h>

#define S_LEN 8192
#define DIM   1024
#define NH    16
#define HD    64
#define WIN   1024
#define GTOK  256
#define QKV_STRIDE (3 * DIM)

typedef __attribute__((ext_vector_type(8))) short bf16x8;
typedef __attribute__((ext_vector_type(4))) float f32x4;
typedef __attribute__((ext_vector_type(16))) float f32x16;
typedef unsigned short u16;
typedef uint32_t u32;

__device__ __forceinline__ u16 f2bf(float f) {
  union { float f; uint32_t u; } v; v.f = f;
  uint32_t r = v.u + 0x7fffu + ((v.u >> 16) & 1u);
  return (u16)(r >> 16);
}
__device__ __forceinline__ float bf2f(u16 b) {
  union { uint32_t u; float f; } v; v.u = ((uint32_t)b) << 16;
  return v.f;
}
__device__ __forceinline__ uint32_t cvtpk(float a, float b) {
  uint32_t r;
  asm("v_cvt_pk_bf16_f32 %0, %1, %2" : "=v"(r) : "v"(a), "v"(b));
  return r;
}

__device__ __forceinline__ void gload_lds16(const void* g, void* l) {
  __builtin_amdgcn_global_load_lds((const __attribute__((address_space(1))) void*)g,
                                   (__attribute__((address_space(3))) void*)l, 16, 0, 0);
}

// ---------------- RMSNorm + scorer ----------------
__global__ __launch_bounds__(256) void rmsnorm_score_kernel(
    const float* __restrict__ x, const float* __restrict__ nw,
    const float* __restrict__ sw, const float* __restrict__ sb,
    u16* __restrict__ h, float* __restrict__ scores) {
  int row = blockIdx.x, tid = threadIdx.x;
  const float4* xr = (const float4*)(x + (size_t)row * DIM);
  float4 v = xr[tid];
  float ss = v.x * v.x + v.y * v.y + v.z * v.z + v.w * v.w;
#pragma unroll
  for (int o = 32; o >= 1; o >>= 1) ss += __shfl_xor(ss, o);
  __shared__ float red[4], red2[4];
  int wv = tid >> 6;
  if ((tid & 63) == 0) red[wv] = ss;
  __syncthreads();
  ss = red[0] + red[1] + red[2] + red[3];
  float rn = rsqrtf(ss * (1.0f / DIM) + 1e-6f);
  float4 w4 = ((const float4*)nw)[tid];
  float h0 = v.x * rn * w4.x, h1 = v.y * rn * w4.y;
  float h2 = v.z * rn * w4.z, h3 = v.w * rn * w4.w;
  uint64_t pack = (uint64_t)f2bf(h0) | ((uint64_t)f2bf(h1) << 16) |
                  ((uint64_t)f2bf(h2) << 32) | ((uint64_t)f2bf(h3) << 48);
  *(uint64_t*)(h + (size_t)row * DIM + tid * 4) = pack;
  float4 s4 = ((const float4*)sw)[tid];
  float sc = h0 * s4.x + h1 * s4.y + h2 * s4.z + h3 * s4.w;
#pragma unroll
  for (int o = 32; o >= 1; o >>= 1) sc += __shfl_xor(sc, o);
  if ((tid & 63) == 0) red2[wv] = sc;
  __syncthreads();
  if (tid == 0) scores[row] = red2[0] + red2[1] + red2[2] + red2[3] + sb[0];
}

// ---------------- weight transpose + bf16 convert ----------------
__global__ __launch_bounds__(256) void transpose_w_kernel(
    const float* __restrict__ wq, const float* __restrict__ wk,
    const float* __restrict__ wv, const float* __restrict__ wo,
    u16* __restrict__ wqkvT, u16* __restrict__ woutT) {
  __shared__ float tile[32][33];
  int z = blockIdx.z;
  const float* src = (z == 0) ? wq : (z == 1) ? wk : (z == 2) ? wv : wo;
  u16* dst = (z < 3) ? (wqkvT + (size_t)z * DIM * DIM) : woutT;
  int tx = threadIdx.x, ty = threadIdx.y;  // 32 x 8
  int n0 = blockIdx.x * 32, k0 = blockIdx.y * 32;
#pragma unroll
  for (int i = 0; i < 4; i++)
    tile[ty + i * 8][tx] = src[(size_t)(k0 + ty + i * 8) * DIM + n0 + tx];
  __syncthreads();
#pragma unroll
  for (int i = 0; i < 4; i++)
    dst[(size_t)(n0 + ty + i * 8) * DIM + k0 + tx] = f2bf(tile[tx][ty + i * 8]);
}

// ---------------- exact top-G by distributed rank counting ----------------
__global__ __launch_bounds__(256) void zero_kernel(int* __restrict__ p) {
  p[blockIdx.x * 256 + threadIdx.x] = 0;
}

__global__ __launch_bounds__(256) void topk_count_kernel(
    const float* __restrict__ scores, int* __restrict__ cnt) {
  __shared__ float sj[1024];
  int jbase = blockIdx.y * 1024;
  for (int t = threadIdx.x; t < 1024; t += 256) sj[t] = scores[jbase + t];
  __syncthreads();
  int i = blockIdx.x * 256 + threadIdx.x;
  float my = scores[i];
  int c = 0;
  const float4* s4 = (const float4*)sj;
#pragma unroll 4
  for (int j = 0; j < 256; j++) {
    float4 v = s4[j];
    int b = jbase + j * 4;
    c += (v.x > my) || (v.x == my && (b + 0) < i);
    c += (v.y > my) || (v.y == my && (b + 1) < i);
    c += (v.z > my) || (v.z == my && (b + 2) < i);
    c += (v.w > my) || (v.w == my && (b + 3) < i);
  }
  if (c) atomicAdd(&cnt[i], c);
}

// rank among SELECTED tokens by token index -> sorted-by-position top-G
__global__ __launch_bounds__(256) void selrank_kernel(
    const int* __restrict__ cnt, int* __restrict__ scnt) {
  __shared__ int sj[1024];
  int jbase = blockIdx.y * 1024;
  for (int t = threadIdx.x; t < 1024; t += 256) sj[t] = (cnt[jbase + t] < GTOK);
  __syncthreads();
  int i = blockIdx.x * 256 + threadIdx.x;
  if (cnt[i] >= GTOK) return;
  int c = 0;
  const int4* s4 = (const int4*)sj;
#pragma unroll 4
  for (int j = 0; j < 256; j++) {
    int4 v = s4[j];
    int b = jbase + j * 4;
    c += (v.x && (b + 0) < i) + (v.y && (b + 1) < i) +
         (v.z && (b + 2) < i) + (v.w && (b + 3) < i);
  }
  if (c) atomicAdd(&scnt[i], c);
}

__global__ __launch_bounds__(256) void selscatter_kernel(
    const int* __restrict__ cnt, const int* __restrict__ scnt, int* __restrict__ gidxS) {
  int i = blockIdx.x * 256 + threadIdx.x;
  if (cnt[i] < GTOK) gidxS[scnt[i]] = i;
}

// ---------------- gather top-G K/V rows (sorted order) ----------------
__global__ __launch_bounds__(128) void gather_kernel(
    const u16* __restrict__ qkv, const int* __restrict__ gidx,
    u16* __restrict__ kg, u16* __restrict__ vg) {
  int g = blockIdx.x, t = threadIdx.x;
  size_t src = (size_t)gidx[g] * QKV_STRIDE;
  *(bf16x8*)(kg + (size_t)g * DIM + t * 8) = *(const bf16x8*)(qkv + src + DIM + t * 8);
  *(bf16x8*)(vg + (size_t)g * DIM + t * 8) = *(const bf16x8*)(qkv + src + 2 * DIM + t * 8);
}

// ---------------- GEMM 256Mx128N tile, 8 waves, BK=64, 3-buf 2-deep counted-vmcnt ----------------
// (round-8 exact version: no XCD swizzle -- T1 hurt here, B panels are L2-resident)
template <int RESID>
__global__ __launch_bounds__(512, 2) void gemm256_kernel(
    const u16* __restrict__ A, const u16* __restrict__ B,
    u16* __restrict__ Cb, float* __restrict__ Cf, const float* __restrict__ X,
    int M, int N, int K) {
  __shared__ __align__(16) u16 As[3][256 * 64];
  __shared__ __align__(16) u16 Bs[3][128 * 64];
  const int tid = threadIdx.x;
  const int wave = tid >> 6, lane = tid & 63;
  const int l15 = lane & 15, l4 = lane >> 4;
  const int wr = wave >> 1, wc = wave & 1;  // 4M x 2N wave grid, 64x64 per wave
  const int mbase = blockIdx.x * 256, nbase = blockIdx.y * 128;
  const int srow = lane >> 3, schunk = lane & 7;
  const int gcol = (schunk ^ srow) * 8;

  auto stage = [&](int tt, int b) {
    const int kt = tt << 6;
#pragma unroll
    for (int q = 0; q < 4; q++) {
      int row = wave * 32 + q * 8;
      gload_lds16(A + (size_t)(mbase + row + srow) * K + kt + gcol, &As[b][row * 64]);
    }
#pragma unroll
    for (int q = 0; q < 2; q++) {
      int row = wave * 16 + q * 8;
      gload_lds16(B + (size_t)(nbase + row + srow) * K + kt + gcol, &Bs[b][row * 64]);
    }
  };

  const int nt = K >> 6;
  f32x4 acc[4][4] = {};

  stage(0, 0);
  stage(1, 1);
  asm volatile("s_waitcnt vmcnt(6)" ::: "memory");
  __builtin_amdgcn_s_barrier();
  __builtin_amdgcn_sched_barrier(0);

  int cur = 0;
  for (int t = 0; t < nt; t++) {
    int pre = cur + 2; if (pre >= 3) pre -= 3;
    if (t + 2 < nt) stage(t + 2, pre);
    const u16* Ab = &As[cur][0];
    const u16* Bb = &Bs[cur][0];
    bf16x8 bfr[4][2], af[4][2];
#pragma unroll
    for (int nf = 0; nf < 4; nf++) {
      int row = wc * 64 + nf * 16 + l15;
#pragma unroll
      for (int kk = 0; kk < 2; kk++)
        bfr[nf][kk] = *(const bf16x8*)(Bb + row * 64 + (((kk * 4 + l4) ^ (l15 & 7)) * 8));
    }
#pragma unroll
    for (int mi = 0; mi < 4; mi++) {
      int row = wr * 64 + mi * 16 + l15;
#pragma unroll
      for (int kk = 0; kk < 2; kk++)
        af[mi][kk] = *(const bf16x8*)(Ab + row * 64 + (((kk * 4 + l4) ^ (l15 & 7)) * 8));
    }
    __builtin_amdgcn_s_setprio(1);
#pragma unroll
    for (int mi = 0; mi < 4; mi++)
#pragma unroll
      for (int nf = 0; nf < 4; nf++)
#pragma unroll
        for (int kk = 0; kk < 2; kk++)
          acc[mi][nf] = __builtin_amdgcn_mfma_f32_16x16x32_bf16(af[mi][kk], bfr[nf][kk],
                                                                acc[mi][nf], 0, 0, 0);
    __builtin_amdgcn_s_setprio(0);
    if (t + 1 < nt) {
      if (t + 2 < nt) asm volatile("s_waitcnt vmcnt(6)" ::: "memory");
      else            asm volatile("s_waitcnt vmcnt(0)" ::: "memory");
      __builtin_amdgcn_s_barrier();
      __builtin_amdgcn_sched_barrier(0);
    }
    cur = (cur + 1 == 3) ? 0 : cur + 1;
  }

#pragma unroll
  for (int mi = 0; mi < 4; mi++) {
#pragma unroll
    for (int nf = 0; nf < 4; nf++) {
#pragma unroll
      for (int r = 0; r < 4; r++) {
        int row = mbase + wr * 64 + mi * 16 + l4 * 4 + r;
        int col = nbase + wc * 64 + nf * 16 + l15;
        float v = acc[mi][nf][r];
        if (RESID) Cf[(size_t)row * N + col] = X[(size_t)row * N + col] + v;
        else       Cb[(size_t)row * N + col] = f2bf(v);
      }
    }
  }
}

// ---------------- fused flash attention v8: sorted-global suffix skip, no spill ----------------
// 8 waves, one 256-q supertile/block, 512 blocks, launch_bounds(512) (VGPR 84, no spill).
// gidx sorted by position => valid global tiles are a prefix (gcount); waves
// additionally skip tiles whose min gpos exceeds their qwmax.
__global__ __launch_bounds__(512) void attn_kernel(
    const u16* __restrict__ qkv, const u16* __restrict__ kg,
    const u16* __restrict__ vg, const int* __restrict__ gidx,
    u16* __restrict__ o) {
  __shared__ __align__(16) u16 kT[2][64][72];   // [buf][key][d] (+8 pad)
  __shared__ __align__(16) u16 vT[2][64][72];   // [buf][d][key^((d>>4)<<4)]
  __shared__ int gposLds[2][64];
  const int tid = threadIdx.x, wave = tid >> 6, lane = tid & 63;
  const int l31 = lane & 31, hi = lane >> 5;

  // work-balanced (head, window, supertile) from dispatch rank
  const int r = blockIdx.x + 32 * blockIdx.y;   // [0,512)
  const int half = r >> 8, rr = r & 255;
  const int h = rr >> 4, w8 = rr & 7, jj = (rr >> 3) & 1;
  const int j = half ? (jj ? 1 : 0) : (jj ? 2 : 3);
  const int wbase = w8 * WIN;
  const int hoff = h * HD;
  const int qsbase = wbase + j * 256;
  const int nLocal = (j + 1) * 4;
  const int qsmax = qsbase + 255;
  // suffix skip: gidx sorted ascending -> valid global tiles are a prefix
  int gcount = 0;
#pragma unroll
  for (int g = 0; g < 4; g++) gcount += (gidx[g * 64] <= qsmax) ? 1 : 0;
  const int nTiles = nLocal + gcount;
  const int qrow = qsbase + wave * 32 + l31;
  const int qwmax = qsbase + wave * 32 + 31;

  // staging map: thread covers key=skey, dims sd8..sd8+7
  const int skey = tid >> 3, sd8 = (tid & 7) * 8;
  const int vcol = skey ^ ((sd8 >> 4) << 4);

  // Q B-fragments with scale*log2e folded in
  bf16x8 qf[4];
  {
    const float SC2 = 0.125f * 1.44269504088896f;
    const u16* qptr = qkv + (size_t)qrow * QKV_STRIDE + hoff + hi * 8;
#pragma unroll
    for (int ks = 0; ks < 4; ks++) {
      bf16x8 raw = *(const bf16x8*)(qptr + ks * 16);
      bf16x8 sc;
#pragma unroll
      for (int t = 0; t < 8; t++) sc[t] = (short)f2bf(bf2f((u16)raw[t]) * SC2);
      qf[ks] = sc;
    }
  }

  // prologue prefetch: window tile 0
  bf16x8 nk, nv;
  int ng = 0;
  {
    const u16* base = qkv + (size_t)(wbase + skey) * QKV_STRIDE + hoff + sd8;
    nk = *(const bf16x8*)(base + DIM);
    nv = *(const bf16x8*)(base + 2 * DIM);
  }

  f32x16 acc0 = {}, acc1 = {};
  float mr = -3.0e38f, lr = 0.f;

  for (int t = 0; t < nTiles; t++) {
    const int p = t & 1;
    const bool isLocal = (t < nLocal);
    const int tbase = wbase + t * 64;
    // ---- stage K (row-major) + V^T (swizzled) + gpos from prefetch regs ----
    *(bf16x8*)(&kT[p][skey][sd8]) = nk;
#pragma unroll
    for (int t8 = 0; t8 < 8; t8++) vT[p][sd8 + t8][vcol] = (u16)nv[t8];
    if (!isLocal && tid < 64) gposLds[p][tid] = ng;
    // ---- prefetch tile t+1 (loads stay in flight across the barrier) ----
    {
      const int nt = t + 1;
      const u16 *ksrc = nullptr, *vsrc = nullptr;
      if (nt < nLocal) {
        const u16* base = qkv + (size_t)(wbase + nt * 64 + skey) * QKV_STRIDE + hoff + sd8;
        ksrc = base + DIM; vsrc = base + 2 * DIM;
      } else if (nt < nTiles) {
        size_t grow = (size_t)((nt - nLocal) * 64 + skey) * DIM + hoff + sd8;
        ksrc = kg + grow; vsrc = vg + grow;
        if (tid < 64) ng = gidx[(nt - nLocal) * 64 + tid];
      }
      if (ksrc) { nk = *(const bf16x8*)(ksrc); nv = *(const bf16x8*)(vsrc); }
    }
    // ---- LDS fence + barrier WITHOUT vmcnt drain ----
    asm volatile("s_waitcnt lgkmcnt(0)" ::: "memory");
    __builtin_amdgcn_s_barrier();
    __builtin_amdgcn_sched_barrier(0);

    // fully-masked tile for this wave -> skip compute
    if (isLocal) {
      if (tbase > qwmax) continue;
    } else {
      if (gposLds[p][0] > qwmax) continue;  // sorted: [0] is the tile minimum
    }

    // ---- QK^T (swapped): S^T[key][q], K from LDS ----
    float sv[32];
    __builtin_amdgcn_s_setprio(1);
#pragma unroll
    for (int kb = 0; kb < 2; kb++) {
      const u16* krow = &kT[p][kb * 32 + l31][hi * 8];
      bf16x8 k0 = *(const bf16x8*)(krow);
      bf16x8 k1 = *(const bf16x8*)(krow + 16);
      bf16x8 k2 = *(const bf16x8*)(krow + 32);
      bf16x8 k3 = *(const bf16x8*)(krow + 48);
      f32x16 z = {};
      z = __builtin_amdgcn_mfma_f32_32x32x16_bf16(k0, qf[0], z, 0, 0, 0);
      z = __builtin_amdgcn_mfma_f32_32x32x16_bf16(k1, qf[1], z, 0, 0, 0);
      z = __builtin_amdgcn_mfma_f32_32x32x16_bf16(k2, qf[2], z, 0, 0, 0);
      z = __builtin_amdgcn_mfma_f32_32x32x16_bf16(k3, qf[3], z, 0, 0, 0);
#pragma unroll
      for (int rg = 0; rg < 16; rg++) sv[kb * 16 + rg] = z[rg];
    }
    __builtin_amdgcn_s_setprio(0);

    // ---- causal mask (scale folded into Q) ----
    if (isLocal) {
      const int lim = qrow - tbase;
      if (lim < 63) {
#pragma unroll
        for (int kb = 0; kb < 2; kb++)
#pragma unroll
          for (int rg = 0; rg < 16; rg++) {
            int crow = kb * 32 + (rg & 3) + 8 * (rg >> 2) + 4 * hi;
            if (crow > lim) sv[kb * 16 + rg] = -3.0e38f;
          }
      }
    } else {
#pragma unroll
      for (int kb = 0; kb < 2; kb++)
#pragma unroll
        for (int rg = 0; rg < 16; rg++) {
          int kpos = gposLds[p][kb * 32 + (rg & 3) + 8 * (rg >> 2) + 4 * hi];
          if (kpos > qrow) sv[kb * 16 + rg] = -3.0e38f;
        }
    }

    // ---- lane-local online softmax with defer-max ----
    float m0 = sv[0], m1 = sv[1], m2 = sv[2], m3 = sv[3];
#pragma unroll
    for (int i = 4; i < 32; i += 4) {
      m0 = fmaxf(m0, sv[i]);     m1 = fmaxf(m1, sv[i + 1]);
      m2 = fmaxf(m2, sv[i + 2]); m3 = fmaxf(m3, sv[i + 3]);
    }
    float vmax = fmaxf(fmaxf(m0, m1), fmaxf(m2, m3));
    vmax = fmaxf(vmax, __shfl_xor(vmax, 32));
    if (__any(vmax > mr + 11.0f)) {
      float mn = fmaxf(mr, vmax);
      float al = exp2f(mr - mn);
      lr *= al;
      mr = mn;
#pragma unroll
      for (int i = 0; i < 16; i++) { acc0[i] *= al; acc1[i] *= al; }
    }
    float s0 = 0.f, s1 = 0.f, s2 = 0.f, s3 = 0.f;
#pragma unroll
    for (int i = 0; i < 32; i += 4) {
      float p0 = exp2f(sv[i] - mr),     p1 = exp2f(sv[i + 1] - mr);
      float p2 = exp2f(sv[i + 2] - mr), p3 = exp2f(sv[i + 3] - mr);
      sv[i] = p0; sv[i + 1] = p1; sv[i + 2] = p2; sv[i + 3] = p3;
      s0 += p0; s1 += p1; s2 += p2; s3 += p3;
    }
    float ps = (s0 + s1) + (s2 + s3);
    ps += __shfl_xor(ps, 32);
    lr += ps;

    // ---- build P B-fragments in-register (cvt_pk + half-swap with lane^32) ----
    bf16x8 pf[4];
#pragma unroll
    for (int q4 = 0; q4 < 4; q4++) {
      int b = q4 * 8;
      uint32_t w0 = cvtpk(sv[b + 0], sv[b + 1]);
      uint32_t w1 = cvtpk(sv[b + 2], sv[b + 3]);
      uint32_t w2 = cvtpk(sv[b + 4], sv[b + 5]);
      uint32_t w3 = cvtpk(sv[b + 6], sv[b + 7]);
      uint32_t w0s = __shfl_xor((int)w0, 32), w2s = __shfl_xor((int)w2, 32);
      uint32_t w1s = __shfl_xor((int)w1, 32), w3s = __shfl_xor((int)w3, 32);
      union { uint32_t w[4]; bf16x8 v; } u;
      u.w[0] = hi ? w2s : w0;
      u.w[1] = hi ? w3s : w1;
      u.w[2] = hi ? w2 : w0s;
      u.w[3] = hi ? w3 : w1s;
      pf[q4] = u.v;
    }

    // ---- PV: O^T[d][q] = mfma(V^T, P) ----
    __builtin_amdgcn_s_setprio(1);
#pragma unroll
    for (int dblk = 0; dblk < 2; dblk++) {
      const int swz = (dblk * 2 + (l31 >> 4)) << 4;
      const u16* vrow = &vT[p][dblk * 32 + l31][0];
      f32x16 a = dblk ? acc1 : acc0;
#pragma unroll
      for (int ksg = 0; ksg < 4; ksg++) {
        bf16x8 vf = *(const bf16x8*)(vrow + ((ksg * 16 + hi * 8) ^ swz));
        a = __builtin_amdgcn_mfma_f32_32x32x16_bf16(vf, pf[ksg], a, 0, 0, 0);
      }
      if (dblk) acc1 = a; else acc0 = a;
    }
    __builtin_amdgcn_s_setprio(0);
  }

  // ---- normalize (lane-local) + store O ----
  float inv = 1.0f / lr;
#pragma unroll
  for (int dblk = 0; dblk < 2; dblk++) {
    f32x16 a = dblk ? acc1 : acc0;
#pragma unroll
    for (int g = 0; g < 4; g++) {
      uint64_t pk = (uint64_t)f2bf(a[g * 4 + 0] * inv)
                  | ((uint64_t)f2bf(a[g * 4 + 1] * inv) << 16)
                  | ((uint64_t)f2bf(a[g * 4 + 2] * inv) << 32)
                  | ((uint64_t)f2bf(a[g * 4 + 3] * inv) << 48);
      *(uint64_t*)(o + (size_t)qrow * DIM + hoff + dblk * 32 + g * 8 + 4 * hi) = pk;
    }
  }
}

// ---------------- launch ----------------
extern "C" void kernel_launch(void* const* d_in, const int* in_sizes, int n_in,
                              void* d_out, int out_size, void* d_ws, size_t ws_size,
                              hipStream_t stream) {
  const float* x  = (const float*)d_in[0];
  const float* nw = (const float*)d_in[1];
  const float* wq = (const float*)d_in[2];
  const float* wk = (const float*)d_in[3];
  const float* wv = (const float*)d_in[4];
  const float* wo = (const float*)d_in[5];
  const float* sw = (const float*)d_in[6];
  const float* sb = (const float*)d_in[7];
  float* out = (float*)d_out;

  char* ws = (char*)d_ws;
  size_t off = 0;
  auto alloc = [&](size_t b) {
    char* p = ws + off;
    off = (off + b + 255) & ~(size_t)255;
    return p;
  };
  u16*   h      = (u16*)alloc((size_t)S_LEN * DIM * 2);
  u16*   wqkvT  = (u16*)alloc((size_t)3 * DIM * DIM * 2);
  u16*   woutT  = (u16*)alloc((size_t)DIM * DIM * 2);
  u16*   qkv    = (u16*)alloc((size_t)S_LEN * 3 * DIM * 2);
  u16*   obuf   = (u16*)alloc((size_t)S_LEN * DIM * 2);
  float* scores = (float*)alloc((size_t)S_LEN * 4);
  int*   cnt    = (int*)alloc((size_t)S_LEN * 4);
  int*   scnt   = (int*)alloc((size_t)S_LEN * 4);
  int*   gidxS  = (int*)alloc((size_t)GTOK * 4);
  u16*   kgbuf  = (u16*)alloc((size_t)GTOK * DIM * 2);
  u16*   vgbuf  = (u16*)alloc((size_t)GTOK * DIM * 2);

  transpose_w_kernel<<<dim3(32, 32, 4), dim3(32, 8), 0, stream>>>(wq, wk, wv, wo, wqkvT, woutT);
  rmsnorm_score_kernel<<<dim3(S_LEN), dim3(256), 0, stream>>>(x, nw, sw, sb, h, scores);
  zero_kernel<<<dim3(S_LEN / 256), dim3(256), 0, stream>>>(cnt);
  zero_kernel<<<dim3(S_LEN / 256), dim3(256), 0, stream>>>(scnt);
  topk_count_kernel<<<dim3(32, 8), dim3(256), 0, stream>>>(scores, cnt);
  selrank_kernel<<<dim3(32, 8), dim3(256), 0, stream>>>(cnt, scnt);
  selscatter_kernel<<<dim3(S_LEN / 256), dim3(256), 0, stream>>>(cnt, scnt, gidxS);
  gemm256_kernel<0><<<dim3(32, 24), dim3(512), 0, stream>>>(h, wqkvT, qkv, nullptr, nullptr,
                                                            S_LEN, 3 * DIM, DIM);
  gather_kernel<<<dim3(GTOK), dim3(128), 0, stream>>>(qkv, gidxS, kgbuf, vgbuf);
  attn_kernel<<<dim3(32, NH), dim3(512), 0, stream>>>(qkv, kgbuf, vgbuf, gidxS, obuf);
  gemm256_kernel<1><<<dim3(32, 8), dim3(512), 0, stream>>>(obuf, woutT, nullptr, out, x,
                                                           S_LEN, DIM, DIM);
}

// Round 11
// 235.597 us; speedup vs baseline: 1.2313x; 1.1203x over previous
//
#include <hip/hip_runtime.h>
#include <stdint.h>

#define S_LEN 8192
#define DIM   1024
#define NH    16
#define HD    64
#define WIN   1024
#define GTOK  256
#define QKV_STRIDE (3 * DIM)

typedef __attribute__((ext_vector_type(8))) short bf16x8;
typedef __attribute__((ext_vector_type(4))) float f32x4;
typedef __attribute__((ext_vector_type(16))) float f32x16;
typedef unsigned short u16;
typedef uint32_t u32;

__device__ __forceinline__ u16 f2bf(float f) {
  union { float f; uint32_t u; } v; v.f = f;
  uint32_t r = v.u + 0x7fffu + ((v.u >> 16) & 1u);
  return (u16)(r >> 16);
}
__device__ __forceinline__ float bf2f(u16 b) {
  union { uint32_t u; float f; } v; v.u = ((uint32_t)b) << 16;
  return v.f;
}
__device__ __forceinline__ uint32_t cvtpk(float a, float b) {
  uint32_t r;
  asm("v_cvt_pk_bf16_f32 %0, %1, %2" : "=v"(r) : "v"(a), "v"(b));
  return r;
}

__device__ __forceinline__ void gload_lds16(const void* g, void* l) {
  __builtin_amdgcn_global_load_lds((const __attribute__((address_space(1))) void*)g,
                                   (__attribute__((address_space(3))) void*)l, 16, 0, 0);
}

// ---------------- RMSNorm + scorer (+ cnt zeroing for topk) ----------------
__global__ __launch_bounds__(256) void rmsnorm_score_kernel(
    const float* __restrict__ x, const float* __restrict__ nw,
    const float* __restrict__ sw, const float* __restrict__ sb,
    u16* __restrict__ h, float* __restrict__ scores, int* __restrict__ cnt) {
  int row = blockIdx.x, tid = threadIdx.x;
  const float4* xr = (const float4*)(x + (size_t)row * DIM);
  float4 v = xr[tid];
  float ss = v.x * v.x + v.y * v.y + v.z * v.z + v.w * v.w;
#pragma unroll
  for (int o = 32; o >= 1; o >>= 1) ss += __shfl_xor(ss, o);
  __shared__ float red[4], red2[4];
  int wv = tid >> 6;
  if ((tid & 63) == 0) red[wv] = ss;
  __syncthreads();
  ss = red[0] + red[1] + red[2] + red[3];
  float rn = rsqrtf(ss * (1.0f / DIM) + 1e-6f);
  float4 w4 = ((const float4*)nw)[tid];
  float h0 = v.x * rn * w4.x, h1 = v.y * rn * w4.y;
  float h2 = v.z * rn * w4.z, h3 = v.w * rn * w4.w;
  uint64_t pack = (uint64_t)f2bf(h0) | ((uint64_t)f2bf(h1) << 16) |
                  ((uint64_t)f2bf(h2) << 32) | ((uint64_t)f2bf(h3) << 48);
  *(uint64_t*)(h + (size_t)row * DIM + tid * 4) = pack;
  float4 s4 = ((const float4*)sw)[tid];
  float sc = h0 * s4.x + h1 * s4.y + h2 * s4.z + h3 * s4.w;
#pragma unroll
  for (int o = 32; o >= 1; o >>= 1) sc += __shfl_xor(sc, o);
  if ((tid & 63) == 0) red2[wv] = sc;
  __syncthreads();
  if (tid == 0) {
    scores[row] = red2[0] + red2[1] + red2[2] + red2[3] + sb[0];
    cnt[row] = 0;
  }
}

// ---------------- weight transpose + bf16 convert ----------------
__global__ __launch_bounds__(256) void transpose_w_kernel(
    const float* __restrict__ wq, const float* __restrict__ wk,
    const float* __restrict__ wv, const float* __restrict__ wo,
    u16* __restrict__ wqkvT, u16* __restrict__ woutT) {
  __shared__ float tile[32][33];
  int z = blockIdx.z;
  const float* src = (z == 0) ? wq : (z == 1) ? wk : (z == 2) ? wv : wo;
  u16* dst = (z < 3) ? (wqkvT + (size_t)z * DIM * DIM) : woutT;
  int tx = threadIdx.x, ty = threadIdx.y;  // 32 x 8
  int n0 = blockIdx.x * 32, k0 = blockIdx.y * 32;
#pragma unroll
  for (int i = 0; i < 4; i++)
    tile[ty + i * 8][tx] = src[(size_t)(k0 + ty + i * 8) * DIM + n0 + tx];
  __syncthreads();
#pragma unroll
  for (int i = 0; i < 4; i++)
    dst[(size_t)(n0 + ty + i * 8) * DIM + k0 + tx] = f2bf(tile[tx][ty + i * 8]);
}

// ---------------- exact top-G by distributed rank counting ----------------
__global__ __launch_bounds__(256) void topk_count_kernel(
    const float* __restrict__ scores, int* __restrict__ cnt) {
  __shared__ float sj[1024];
  int jbase = blockIdx.y * 1024;
  for (int t = threadIdx.x; t < 1024; t += 256) sj[t] = scores[jbase + t];
  __syncthreads();
  int i = blockIdx.x * 256 + threadIdx.x;
  float my = scores[i];
  int c = 0;
  const float4* s4 = (const float4*)sj;
#pragma unroll 4
  for (int j = 0; j < 256; j++) {
    float4 v = s4[j];
    int b = jbase + j * 4;
    c += (v.x > my) || (v.x == my && (b + 0) < i);
    c += (v.y > my) || (v.y == my && (b + 1) < i);
    c += (v.z > my) || (v.z == my && (b + 2) < i);
    c += (v.w > my) || (v.w == my && (b + 3) < i);
  }
  if (c) atomicAdd(&cnt[i], c);
}

__global__ __launch_bounds__(256) void topk_scatter_kernel(
    const int* __restrict__ cnt, int* __restrict__ gidx) {
  int i = blockIdx.x * 256 + threadIdx.x;
  int c = cnt[i];
  if (c < GTOK) gidx[c] = i;
}

// ---------------- gather top-G K/V rows ----------------
__global__ __launch_bounds__(128) void gather_kernel(
    const u16* __restrict__ qkv, const int* __restrict__ gidx,
    u16* __restrict__ kg, u16* __restrict__ vg) {
  int g = blockIdx.x, t = threadIdx.x;
  size_t src = (size_t)gidx[g] * QKV_STRIDE;
  *(bf16x8*)(kg + (size_t)g * DIM + t * 8) = *(const bf16x8*)(qkv + src + DIM + t * 8);
  *(bf16x8*)(vg + (size_t)g * DIM + t * 8) = *(const bf16x8*)(qkv + src + 2 * DIM + t * 8);
}

// ---------------- GEMM 256Mx128N tile, 8 waves, BK=64, 3-buf 2-deep counted-vmcnt ----------------
// (round-8 exact version)
template <int RESID>
__global__ __launch_bounds__(512, 2) void gemm256_kernel(
    const u16* __restrict__ A, const u16* __restrict__ B,
    u16* __restrict__ Cb, float* __restrict__ Cf, const float* __restrict__ X,
    int M, int N, int K) {
  __shared__ __align__(16) u16 As[3][256 * 64];
  __shared__ __align__(16) u16 Bs[3][128 * 64];
  const int tid = threadIdx.x;
  const int wave = tid >> 6, lane = tid & 63;
  const int l15 = lane & 15, l4 = lane >> 4;
  const int wr = wave >> 1, wc = wave & 1;  // 4M x 2N wave grid, 64x64 per wave
  const int mbase = blockIdx.x * 256, nbase = blockIdx.y * 128;
  const int srow = lane >> 3, schunk = lane & 7;
  const int gcol = (schunk ^ srow) * 8;

  auto stage = [&](int tt, int b) {
    const int kt = tt << 6;
#pragma unroll
    for (int q = 0; q < 4; q++) {
      int row = wave * 32 + q * 8;
      gload_lds16(A + (size_t)(mbase + row + srow) * K + kt + gcol, &As[b][row * 64]);
    }
#pragma unroll
    for (int q = 0; q < 2; q++) {
      int row = wave * 16 + q * 8;
      gload_lds16(B + (size_t)(nbase + row + srow) * K + kt + gcol, &Bs[b][row * 64]);
    }
  };

  const int nt = K >> 6;
  f32x4 acc[4][4] = {};

  stage(0, 0);
  stage(1, 1);
  asm volatile("s_waitcnt vmcnt(6)" ::: "memory");
  __builtin_amdgcn_s_barrier();
  __builtin_amdgcn_sched_barrier(0);

  int cur = 0;
  for (int t = 0; t < nt; t++) {
    int pre = cur + 2; if (pre >= 3) pre -= 3;
    if (t + 2 < nt) stage(t + 2, pre);
    const u16* Ab = &As[cur][0];
    const u16* Bb = &Bs[cur][0];
    bf16x8 bfr[4][2], af[4][2];
#pragma unroll
    for (int nf = 0; nf < 4; nf++) {
      int row = wc * 64 + nf * 16 + l15;
#pragma unroll
      for (int kk = 0; kk < 2; kk++)
        bfr[nf][kk] = *(const bf16x8*)(Bb + row * 64 + (((kk * 4 + l4) ^ (l15 & 7)) * 8));
    }
#pragma unroll
    for (int mi = 0; mi < 4; mi++) {
      int row = wr * 64 + mi * 16 + l15;
#pragma unroll
      for (int kk = 0; kk < 2; kk++)
        af[mi][kk] = *(const bf16x8*)(Ab + row * 64 + (((kk * 4 + l4) ^ (l15 & 7)) * 8));
    }
    __builtin_amdgcn_s_setprio(1);
#pragma unroll
    for (int mi = 0; mi < 4; mi++)
#pragma unroll
      for (int nf = 0; nf < 4; nf++)
#pragma unroll
        for (int kk = 0; kk < 2; kk++)
          acc[mi][nf] = __builtin_amdgcn_mfma_f32_16x16x32_bf16(af[mi][kk], bfr[nf][kk],
                                                                acc[mi][nf], 0, 0, 0);
    __builtin_amdgcn_s_setprio(0);
    if (t + 1 < nt) {
      if (t + 2 < nt) asm volatile("s_waitcnt vmcnt(6)" ::: "memory");
      else            asm volatile("s_waitcnt vmcnt(0)" ::: "memory");
      __builtin_amdgcn_s_barrier();
      __builtin_amdgcn_sched_barrier(0);
    }
    cur = (cur + 1 == 3) ? 0 : cur + 1;
  }

#pragma unroll
  for (int mi = 0; mi < 4; mi++) {
#pragma unroll
    for (int nf = 0; nf < 4; nf++) {
#pragma unroll
      for (int r = 0; r < 4; r++) {
        int row = mbase + wr * 64 + mi * 16 + l4 * 4 + r;
        int col = nbase + wc * 64 + nf * 16 + l15;
        float v = acc[mi][nf][r];
        if (RESID) Cf[(size_t)row * N + col] = X[(size_t)row * N + col] + v;
        else       Cb[(size_t)row * N + col] = f2bf(v);
      }
    }
  }
}

// ---------------- fused flash attention v9: 32KB LDS (2-blocks/CU experiment) ----------------
// Round-8 structure exactly, but LDS shrunk to 32768B: kT/vT [2][64][64] with
// 16B-chunk XOR swizzle (store (row,col) at chunk (col>>3)^(row&7); reads use the
// same involution), and gposLds replaced by per-wave register + __shfl.
__global__ __launch_bounds__(512) void attn_kernel(
    const u16* __restrict__ qkv, const u16* __restrict__ kg,
    const u16* __restrict__ vg, const int* __restrict__ gidx,
    u16* __restrict__ o) {
  __shared__ __align__(16) u16 kT[2][64][64];   // chunk-XOR swizzled
  __shared__ __align__(16) u16 vT[2][64][64];   // chunk-XOR swizzled (V^T)
  const int tid = threadIdx.x, wave = tid >> 6, lane = tid & 63;
  const int l31 = lane & 31, hi = lane >> 5;
  const int l7 = l31 & 7;

  // work-balanced (head, window, supertile) from dispatch rank
  const int r = blockIdx.x + 32 * blockIdx.y;   // [0,512)
  const int half = r >> 8, rr = r & 255;
  const int h = rr >> 4, w8 = rr & 7, jj = (rr >> 3) & 1;
  const int j = half ? (jj ? 1 : 0) : (jj ? 2 : 3);
  const int wbase = w8 * WIN;
  const int hoff = h * HD;
  const int qsbase = wbase + j * 256;
  const int nLocal = (j + 1) * 4;
  const int nTiles = nLocal + GTOK / 64;
  const int qrow = qsbase + wave * 32 + l31;
  const int qwmax = qsbase + wave * 32 + 31;

  // staging map: thread covers key=skey, chunk=(tid&7) (16B of K), dims sd8..sd8+7 of V
  const int skey = tid >> 3, sd8 = (tid & 7) * 8;
  const int kchunk = ((tid & 7) ^ (skey & 7)) * 8;  // swizzled K chunk offset (u16)

  // Q B-fragments with scale*log2e folded in
  bf16x8 qf[4];
  {
    const float SC2 = 0.125f * 1.44269504088896f;
    const u16* qptr = qkv + (size_t)qrow * QKV_STRIDE + hoff + hi * 8;
#pragma unroll
    for (int ks = 0; ks < 4; ks++) {
      bf16x8 raw = *(const bf16x8*)(qptr + ks * 16);
      bf16x8 sc;
#pragma unroll
      for (int t = 0; t < 8; t++) sc[t] = (short)f2bf(bf2f((u16)raw[t]) * SC2);
      qf[ks] = sc;
    }
  }

  // prologue prefetch: window tile 0
  bf16x8 nk, nv;
  int ngNext = 0, ngCur = 0;
  {
    const u16* base = qkv + (size_t)(wbase + skey) * QKV_STRIDE + hoff + sd8;
    nk = *(const bf16x8*)(base + DIM);
    nv = *(const bf16x8*)(base + 2 * DIM);
  }

  f32x16 acc0 = {}, acc1 = {};
  float mr = -3.0e38f, lr = 0.f;

  for (int t = 0; t < nTiles; t++) {
    const int p = t & 1;
    const bool isLocal = (t < nLocal);
    const int tbase = wbase + t * 64;
    ngCur = ngNext;
    // ---- stage K + V^T (chunk-XOR swizzled) from prefetch regs ----
    *(bf16x8*)(&kT[p][skey][kchunk]) = nk;
#pragma unroll
    for (int t8 = 0; t8 < 8; t8++)
      vT[p][sd8 + t8][((((skey >> 3) ^ t8) & 7) << 3) | (skey & 7)] = (u16)nv[t8];
    // ---- prefetch tile t+1 (loads stay in flight across the barrier) ----
    {
      const int nt = t + 1;
      const u16 *ksrc = nullptr, *vsrc = nullptr;
      if (nt < nLocal) {
        const u16* base = qkv + (size_t)(wbase + nt * 64 + skey) * QKV_STRIDE + hoff + sd8;
        ksrc = base + DIM; vsrc = base + 2 * DIM;
      } else if (nt < nTiles) {
        size_t grow = (size_t)((nt - nLocal) * 64 + skey) * DIM + hoff + sd8;
        ksrc = kg + grow; vsrc = vg + grow;
        ngNext = gidx[(nt - nLocal) * 64 + lane];   // every wave holds all 64 positions
      }
      if (ksrc) { nk = *(const bf16x8*)(ksrc); nv = *(const bf16x8*)(vsrc); }
    }
    // ---- LDS fence + barrier WITHOUT vmcnt drain ----
    asm volatile("s_waitcnt lgkmcnt(0)" ::: "memory");
    __builtin_amdgcn_s_barrier();
    __builtin_amdgcn_sched_barrier(0);

    // fully-masked local tile for this wave -> skip compute
    if (isLocal && tbase > qwmax) continue;

    // ---- QK^T (swapped): S^T[key][q], K from LDS (swizzled reads) ----
    float sv[32];
    __builtin_amdgcn_s_setprio(1);
#pragma unroll
    for (int kb = 0; kb < 2; kb++) {
      const u16* krow = &kT[p][kb * 32 + l31][0];
      bf16x8 k0 = *(const bf16x8*)(krow + (((hi + 0) ^ l7) << 3));
      bf16x8 k1 = *(const bf16x8*)(krow + (((hi + 2) ^ l7) << 3));
      bf16x8 k2 = *(const bf16x8*)(krow + (((hi + 4) ^ l7) << 3));
      bf16x8 k3 = *(const bf16x8*)(krow + (((hi + 6) ^ l7) << 3));
      f32x16 z = {};
      z = __builtin_amdgcn_mfma_f32_32x32x16_bf16(k0, qf[0], z, 0, 0, 0);
      z = __builtin_amdgcn_mfma_f32_32x32x16_bf16(k1, qf[1], z, 0, 0, 0);
      z = __builtin_amdgcn_mfma_f32_32x32x16_bf16(k2, qf[2], z, 0, 0, 0);
      z = __builtin_amdgcn_mfma_f32_32x32x16_bf16(k3, qf[3], z, 0, 0, 0);
#pragma unroll
      for (int rg = 0; rg < 16; rg++) sv[kb * 16 + rg] = z[rg];
    }
    __builtin_amdgcn_s_setprio(0);

    // ---- causal mask (scale folded into Q) ----
    if (isLocal) {
      const int lim = qrow - tbase;
      if (lim < 63) {
#pragma unroll
        for (int kb = 0; kb < 2; kb++)
#pragma unroll
          for (int rg = 0; rg < 16; rg++) {
            int crow = kb * 32 + (rg & 3) + 8 * (rg >> 2) + 4 * hi;
            if (crow > lim) sv[kb * 16 + rg] = -3.0e38f;
          }
      }
    } else {
#pragma unroll
      for (int kb = 0; kb < 2; kb++)
#pragma unroll
        for (int rg = 0; rg < 16; rg++) {
          int kpos = __shfl(ngCur, kb * 32 + (rg & 3) + 8 * (rg >> 2) + 4 * hi);
          if (kpos > qrow) sv[kb * 16 + rg] = -3.0e38f;
        }
    }

    // ---- lane-local online softmax with defer-max ----
    float m0 = sv[0], m1 = sv[1], m2 = sv[2], m3 = sv[3];
#pragma unroll
    for (int i = 4; i < 32; i += 4) {
      m0 = fmaxf(m0, sv[i]);     m1 = fmaxf(m1, sv[i + 1]);
      m2 = fmaxf(m2, sv[i + 2]); m3 = fmaxf(m3, sv[i + 3]);
    }
    float vmax = fmaxf(fmaxf(m0, m1), fmaxf(m2, m3));
    vmax = fmaxf(vmax, __shfl_xor(vmax, 32));
    if (__any(vmax > mr + 11.0f)) {
      float mn = fmaxf(mr, vmax);
      float al = exp2f(mr - mn);
      lr *= al;
      mr = mn;
#pragma unroll
      for (int i = 0; i < 16; i++) { acc0[i] *= al; acc1[i] *= al; }
    }
    float s0 = 0.f, s1 = 0.f, s2 = 0.f, s3 = 0.f;
#pragma unroll
    for (int i = 0; i < 32; i += 4) {
      float p0 = exp2f(sv[i] - mr),     p1 = exp2f(sv[i + 1] - mr);
      float p2 = exp2f(sv[i + 2] - mr), p3 = exp2f(sv[i + 3] - mr);
      sv[i] = p0; sv[i + 1] = p1; sv[i + 2] = p2; sv[i + 3] = p3;
      s0 += p0; s1 += p1; s2 += p2; s3 += p3;
    }
    float ps = (s0 + s1) + (s2 + s3);
    ps += __shfl_xor(ps, 32);
    lr += ps;

    // ---- build P B-fragments in-register (cvt_pk + half-swap with lane^32) ----
    bf16x8 pf[4];
#pragma unroll
    for (int q4 = 0; q4 < 4; q4++) {
      int b = q4 * 8;
      uint32_t w0 = cvtpk(sv[b + 0], sv[b + 1]);
      uint32_t w1 = cvtpk(sv[b + 2], sv[b + 3]);
      uint32_t w2 = cvtpk(sv[b + 4], sv[b + 5]);
      uint32_t w3 = cvtpk(sv[b + 6], sv[b + 7]);
      uint32_t w0s = __shfl_xor((int)w0, 32), w2s = __shfl_xor((int)w2, 32);
      uint32_t w1s = __shfl_xor((int)w1, 32), w3s = __shfl_xor((int)w3, 32);
      union { uint32_t w[4]; bf16x8 v; } u;
      u.w[0] = hi ? w2s : w0;
      u.w[1] = hi ? w3s : w1;
      u.w[2] = hi ? w2 : w0s;
      u.w[3] = hi ? w3 : w1s;
      pf[q4] = u.v;
    }

    // ---- PV: O^T[d][q] = mfma(V^T, P), swizzled reads ----
    __builtin_amdgcn_s_setprio(1);
#pragma unroll
    for (int dblk = 0; dblk < 2; dblk++) {
      const u16* vrow = &vT[p][dblk * 32 + l31][0];
      f32x16 a = dblk ? acc1 : acc0;
#pragma unroll
      for (int ksg = 0; ksg < 4; ksg++) {
        bf16x8 vf = *(const bf16x8*)(vrow + (((hi + 2 * ksg) ^ l7) << 3));
        a = __builtin_amdgcn_mfma_f32_32x32x16_bf16(vf, pf[ksg], a, 0, 0, 0);
      }
      if (dblk) acc1 = a; else acc0 = a;
    }
    __builtin_amdgcn_s_setprio(0);
  }

  // ---- normalize (lane-local) + store O ----
  float inv = 1.0f / lr;
#pragma unroll
  for (int dblk = 0; dblk < 2; dblk++) {
    f32x16 a = dblk ? acc1 : acc0;
#pragma unroll
    for (int g = 0; g < 4; g++) {
      uint64_t pk = (uint64_t)f2bf(a[g * 4 + 0] * inv)
                  | ((uint64_t)f2bf(a[g * 4 + 1] * inv) << 16)
                  | ((uint64_t)f2bf(a[g * 4 + 2] * inv) << 32)
                  | ((uint64_t)f2bf(a[g * 4 + 3] * inv) << 48);
      *(uint64_t*)(o + (size_t)qrow * DIM + hoff + dblk * 32 + g * 8 + 4 * hi) = pk;
    }
  }
}

// ---------------- launch ----------------
extern "C" void kernel_launch(void* const* d_in, const int* in_sizes, int n_in,
                              void* d_out, int out_size, void* d_ws, size_t ws_size,
                              hipStream_t stream) {
  const float* x  = (const float*)d_in[0];
  const float* nw = (const float*)d_in[1];
  const float* wq = (const float*)d_in[2];
  const float* wk = (const float*)d_in[3];
  const float* wv = (const float*)d_in[4];
  const float* wo = (const float*)d_in[5];
  const float* sw = (const float*)d_in[6];
  const float* sb = (const float*)d_in[7];
  float* out = (float*)d_out;

  char* ws = (char*)d_ws;
  size_t off = 0;
  auto alloc = [&](size_t b) {
    char* p = ws + off;
    off = (off + b + 255) & ~(size_t)255;
    return p;
  };
  u16*   h      = (u16*)alloc((size_t)S_LEN * DIM * 2);
  u16*   wqkvT  = (u16*)alloc((size_t)3 * DIM * DIM * 2);
  u16*   woutT  = (u16*)alloc((size_t)DIM * DIM * 2);
  u16*   qkv    = (u16*)alloc((size_t)S_LEN * 3 * DIM * 2);
  u16*   obuf   = (u16*)alloc((size_t)S_LEN * DIM * 2);
  float* scores = (float*)alloc((size_t)S_LEN * 4);
  int*   cnt    = (int*)alloc((size_t)S_LEN * 4);
  int*   gidx   = (int*)alloc((size_t)GTOK * 4);
  u16*   kgbuf  = (u16*)alloc((size_t)GTOK * DIM * 2);
  u16*   vgbuf  = (u16*)alloc((size_t)GTOK * DIM * 2);

  transpose_w_kernel<<<dim3(32, 32, 4), dim3(32, 8), 0, stream>>>(wq, wk, wv, wo, wqkvT, woutT);
  rmsnorm_score_kernel<<<dim3(S_LEN), dim3(256), 0, stream>>>(x, nw, sw, sb, h, scores, cnt);
  topk_count_kernel<<<dim3(32, 8), dim3(256), 0, stream>>>(scores, cnt);
  topk_scatter_kernel<<<dim3(S_LEN / 256), dim3(256), 0, stream>>>(cnt, gidx);
  gemm256_kernel<0><<<dim3(32, 24), dim3(512), 0, stream>>>(h, wqkvT, qkv, nullptr, nullptr,
                                                            S_LEN, 3 * DIM, DIM);
  gather_kernel<<<dim3(GTOK), dim3(128), 0, stream>>>(qkv, gidx, kgbuf, vgbuf);
  attn_kernel<<<dim3(32, NH), dim3(512), 0, stream>>>(qkv, kgbuf, vgbuf, gidx, obuf);
  gemm256_kernel<1><<<dim3(32, 8), dim3(512), 0, stream>>>(obuf, woutT, nullptr, out, x,
                                                           S_LEN, DIM, DIM);
}

// Round 12
// 219.795 us; speedup vs baseline: 1.3198x; 1.0719x over previous
//
#include <hip/hip_runtime.h>
#include <stdint.h>

#define S_LEN 8192
#define DIM   1024
#define NH    16
#define HD    64
#define WIN   1024
#define GTOK  256
#define QKV_STRIDE (3 * DIM)

typedef __attribute__((ext_vector_type(8))) short bf16x8;
typedef __attribute__((ext_vector_type(4))) float f32x4;
typedef __attribute__((ext_vector_type(16))) float f32x16;
typedef unsigned short u16;
typedef uint32_t u32;

__device__ __forceinline__ u16 f2bf(float f) {
  union { float f; uint32_t u; } v; v.f = f;
  uint32_t r = v.u + 0x7fffu + ((v.u >> 16) & 1u);
  return (u16)(r >> 16);
}
__device__ __forceinline__ float bf2f(u16 b) {
  union { uint32_t u; float f; } v; v.u = ((uint32_t)b) << 16;
  return v.f;
}
__device__ __forceinline__ uint32_t cvtpk(float a, float b) {
  uint32_t r;
  asm("v_cvt_pk_bf16_f32 %0, %1, %2" : "=v"(r) : "v"(a), "v"(b));
  return r;
}

__device__ __forceinline__ void gload_lds16(const void* g, void* l) {
  __builtin_amdgcn_global_load_lds((const __attribute__((address_space(1))) void*)g,
                                   (__attribute__((address_space(3))) void*)l, 16, 0, 0);
}

// ---------------- RMSNorm + scorer (+ cnt zeroing for topk) ----------------
__global__ __launch_bounds__(256) void rmsnorm_score_kernel(
    const float* __restrict__ x, const float* __restrict__ nw,
    const float* __restrict__ sw, const float* __restrict__ sb,
    u16* __restrict__ h, float* __restrict__ scores, int* __restrict__ cnt) {
  int row = blockIdx.x, tid = threadIdx.x;
  const float4* xr = (const float4*)(x + (size_t)row * DIM);
  float4 v = xr[tid];
  float ss = v.x * v.x + v.y * v.y + v.z * v.z + v.w * v.w;
#pragma unroll
  for (int o = 32; o >= 1; o >>= 1) ss += __shfl_xor(ss, o);
  __shared__ float red[4], red2[4];
  int wv = tid >> 6;
  if ((tid & 63) == 0) red[wv] = ss;
  __syncthreads();
  ss = red[0] + red[1] + red[2] + red[3];
  float rn = rsqrtf(ss * (1.0f / DIM) + 1e-6f);
  float4 w4 = ((const float4*)nw)[tid];
  float h0 = v.x * rn * w4.x, h1 = v.y * rn * w4.y;
  float h2 = v.z * rn * w4.z, h3 = v.w * rn * w4.w;
  uint64_t pack = (uint64_t)f2bf(h0) | ((uint64_t)f2bf(h1) << 16) |
                  ((uint64_t)f2bf(h2) << 32) | ((uint64_t)f2bf(h3) << 48);
  *(uint64_t*)(h + (size_t)row * DIM + tid * 4) = pack;
  float4 s4 = ((const float4*)sw)[tid];
  float sc = h0 * s4.x + h1 * s4.y + h2 * s4.z + h3 * s4.w;
#pragma unroll
  for (int o = 32; o >= 1; o >>= 1) sc += __shfl_xor(sc, o);
  if ((tid & 63) == 0) red2[wv] = sc;
  __syncthreads();
  if (tid == 0) {
    scores[row] = red2[0] + red2[1] + red2[2] + red2[3] + sb[0];
    cnt[row] = 0;
  }
}

// ---------------- weight transpose + bf16 convert ----------------
__global__ __launch_bounds__(256) void transpose_w_kernel(
    const float* __restrict__ wq, const float* __restrict__ wk,
    const float* __restrict__ wv, const float* __restrict__ wo,
    u16* __restrict__ wqkvT, u16* __restrict__ woutT) {
  __shared__ float tile[32][33];
  int z = blockIdx.z;
  const float* src = (z == 0) ? wq : (z == 1) ? wk : (z == 2) ? wv : wo;
  u16* dst = (z < 3) ? (wqkvT + (size_t)z * DIM * DIM) : woutT;
  int tx = threadIdx.x, ty = threadIdx.y;  // 32 x 8
  int n0 = blockIdx.x * 32, k0 = blockIdx.y * 32;
#pragma unroll
  for (int i = 0; i < 4; i++)
    tile[ty + i * 8][tx] = src[(size_t)(k0 + ty + i * 8) * DIM + n0 + tx];
  __syncthreads();
#pragma unroll
  for (int i = 0; i < 4; i++)
    dst[(size_t)(n0 + ty + i * 8) * DIM + k0 + tx] = f2bf(tile[tx][ty + i * 8]);
}

// ---------------- exact top-G by distributed rank counting ----------------
__global__ __launch_bounds__(256) void topk_count_kernel(
    const float* __restrict__ scores, int* __restrict__ cnt) {
  __shared__ float sj[1024];
  int jbase = blockIdx.y * 1024;
  for (int t = threadIdx.x; t < 1024; t += 256) sj[t] = scores[jbase + t];
  __syncthreads();
  int i = blockIdx.x * 256 + threadIdx.x;
  float my = scores[i];
  int c = 0;
  const float4* s4 = (const float4*)sj;
#pragma unroll 4
  for (int j = 0; j < 256; j++) {
    float4 v = s4[j];
    int b = jbase + j * 4;
    c += (v.x > my) || (v.x == my && (b + 0) < i);
    c += (v.y > my) || (v.y == my && (b + 1) < i);
    c += (v.z > my) || (v.z == my && (b + 2) < i);
    c += (v.w > my) || (v.w == my && (b + 3) < i);
  }
  if (c) atomicAdd(&cnt[i], c);
}

__global__ __launch_bounds__(256) void topk_scatter_kernel(
    const int* __restrict__ cnt, int* __restrict__ gidx) {
  int i = blockIdx.x * 256 + threadIdx.x;
  int c = cnt[i];
  if (c < GTOK) gidx[c] = i;
}

// ---------------- gather top-G K/V rows ----------------
__global__ __launch_bounds__(128) void gather_kernel(
    const u16* __restrict__ qkv, const int* __restrict__ gidx,
    u16* __restrict__ kg, u16* __restrict__ vg) {
  int g = blockIdx.x, t = threadIdx.x;
  size_t src = (size_t)gidx[g] * QKV_STRIDE;
  *(bf16x8*)(kg + (size_t)g * DIM + t * 8) = *(const bf16x8*)(qkv + src + DIM + t * 8);
  *(bf16x8*)(vg + (size_t)g * DIM + t * 8) = *(const bf16x8*)(qkv + src + 2 * DIM + t * 8);
}

// ---------------- GEMM 256Mx128N tile, 8 waves, BK=64, 3-buf 2-deep counted-vmcnt ----------------
// (round-8 exact version -- best measured GEMM)
template <int RESID>
__global__ __launch_bounds__(512, 2) void gemm256_kernel(
    const u16* __restrict__ A, const u16* __restrict__ B,
    u16* __restrict__ Cb, float* __restrict__ Cf, const float* __restrict__ X,
    int M, int N, int K) {
  __shared__ __align__(16) u16 As[3][256 * 64];
  __shared__ __align__(16) u16 Bs[3][128 * 64];
  const int tid = threadIdx.x;
  const int wave = tid >> 6, lane = tid & 63;
  const int l15 = lane & 15, l4 = lane >> 4;
  const int wr = wave >> 1, wc = wave & 1;  // 4M x 2N wave grid, 64x64 per wave
  const int mbase = blockIdx.x * 256, nbase = blockIdx.y * 128;
  const int srow = lane >> 3, schunk = lane & 7;
  const int gcol = (schunk ^ srow) * 8;

  auto stage = [&](int tt, int b) {
    const int kt = tt << 6;
#pragma unroll
    for (int q = 0; q < 4; q++) {
      int row = wave * 32 + q * 8;
      gload_lds16(A + (size_t)(mbase + row + srow) * K + kt + gcol, &As[b][row * 64]);
    }
#pragma unroll
    for (int q = 0; q < 2; q++) {
      int row = wave * 16 + q * 8;
      gload_lds16(B + (size_t)(nbase + row + srow) * K + kt + gcol, &Bs[b][row * 64]);
    }
  };

  const int nt = K >> 6;
  f32x4 acc[4][4] = {};

  stage(0, 0);
  stage(1, 1);
  asm volatile("s_waitcnt vmcnt(6)" ::: "memory");
  __builtin_amdgcn_s_barrier();
  __builtin_amdgcn_sched_barrier(0);

  int cur = 0;
  for (int t = 0; t < nt; t++) {
    int pre = cur + 2; if (pre >= 3) pre -= 3;
    if (t + 2 < nt) stage(t + 2, pre);
    const u16* Ab = &As[cur][0];
    const u16* Bb = &Bs[cur][0];
    bf16x8 bfr[4][2], af[4][2];
#pragma unroll
    for (int nf = 0; nf < 4; nf++) {
      int row = wc * 64 + nf * 16 + l15;
#pragma unroll
      for (int kk = 0; kk < 2; kk++)
        bfr[nf][kk] = *(const bf16x8*)(Bb + row * 64 + (((kk * 4 + l4) ^ (l15 & 7)) * 8));
    }
#pragma unroll
    for (int mi = 0; mi < 4; mi++) {
      int row = wr * 64 + mi * 16 + l15;
#pragma unroll
      for (int kk = 0; kk < 2; kk++)
        af[mi][kk] = *(const bf16x8*)(Ab + row * 64 + (((kk * 4 + l4) ^ (l15 & 7)) * 8));
    }
    __builtin_amdgcn_s_setprio(1);
#pragma unroll
    for (int mi = 0; mi < 4; mi++)
#pragma unroll
      for (int nf = 0; nf < 4; nf++)
#pragma unroll
        for (int kk = 0; kk < 2; kk++)
          acc[mi][nf] = __builtin_amdgcn_mfma_f32_16x16x32_bf16(af[mi][kk], bfr[nf][kk],
                                                                acc[mi][nf], 0, 0, 0);
    __builtin_amdgcn_s_setprio(0);
    if (t + 1 < nt) {
      if (t + 2 < nt) asm volatile("s_waitcnt vmcnt(6)" ::: "memory");
      else            asm volatile("s_waitcnt vmcnt(0)" ::: "memory");
      __builtin_amdgcn_s_barrier();
      __builtin_amdgcn_sched_barrier(0);
    }
    cur = (cur + 1 == 3) ? 0 : cur + 1;
  }

#pragma unroll
  for (int mi = 0; mi < 4; mi++) {
#pragma unroll
    for (int nf = 0; nf < 4; nf++) {
#pragma unroll
      for (int r = 0; r < 4; r++) {
        int row = mbase + wr * 64 + mi * 16 + l4 * 4 + r;
        int col = nbase + wc * 64 + nf * 16 + l15;
        float v = acc[mi][nf][r];
        if (RESID) Cf[(size_t)row * N + col] = X[(size_t)row * N + col] + v;
        else       Cb[(size_t)row * N + col] = f2bf(v);
      }
    }
  }
}

// ---------------- fused flash attention (round-6 exact: best measured, 86.8us) ----------------
// Block = 8 waves x 32 q = 256 q supertile; processes supertiles {pair, 3-pair} of its
// window sequentially -> every block does exactly 20 local + 8 global = 28 KV tiles.
// 256 blocks = 1/CU, perfectly balanced. pad-72 kT, XOR-16 vT, __syncthreads per tile.
__global__ __launch_bounds__(512) void attn_kernel(
    const u16* __restrict__ qkv, const u16* __restrict__ kg,
    const u16* __restrict__ vg, const int* __restrict__ gidx,
    u16* __restrict__ o) {
  __shared__ u16 kT[2][64][72];   // [buf][key][d] (+8 pad)
  __shared__ u16 vT[2][64][72];   // [buf][d][key^((d>>4)<<4)]
  __shared__ int gposLds[2][64];
  const int tid = threadIdx.x, wave = tid >> 6, lane = tid & 63;
  const int l31 = lane & 31, hi = lane >> 5;
  const int win = blockIdx.x >> 1, pair = blockIdx.x & 1;
  const int wbase = win * WIN;
  const int hoff = blockIdx.y * HD;

  // staging map: thread covers key=skey, dims sd8..sd8+7 (16 B of K and of V)
  const int skey = tid >> 3, sd8 = (tid & 7) * 8;
  const int vcol = skey ^ ((sd8 >> 4) << 4);

  // prologue prefetch: window tile 0 (shared by both supertiles' t=0)
  bf16x8 nk, nv;
  int ng = 0;
  {
    const u16* base = qkv + (size_t)(wbase + skey) * QKV_STRIDE + hoff + sd8;
    nk = *(const bf16x8*)(base + DIM);
    nv = *(const bf16x8*)(base + 2 * DIM);
  }

  for (int sp = 0; sp < 2; sp++) {
    const int j = sp ? (3 - pair) : pair;          // supertile index in window
    const int qsbase = wbase + j * 256;
    const int nLocal = (j + 1) * 4;
    const int nTiles = nLocal + GTOK / 64;
    const int qrow = qsbase + wave * 32 + l31;
    const int qwmax = qsbase + wave * 32 + 31;

    // Q B-fragments with scale*log2e folded in
    bf16x8 qf[4];
    {
      const float SC2 = 0.125f * 1.44269504088896f;
      const u16* qptr = qkv + (size_t)qrow * QKV_STRIDE + hoff + hi * 8;
#pragma unroll
      for (int ks = 0; ks < 4; ks++) {
        bf16x8 raw = *(const bf16x8*)(qptr + ks * 16);
        bf16x8 sc;
#pragma unroll
        for (int jj = 0; jj < 8; jj++) sc[jj] = (short)f2bf(bf2f((u16)raw[jj]) * SC2);
        qf[ks] = sc;
      }
    }

    f32x16 acc0 = {}, acc1 = {};
    float mr = -3.0e38f, lr = 0.f;

    __syncthreads();  // all waves done with LDS buffers from previous supertile

    for (int t = 0; t < nTiles; t++) {
      const int p = t & 1;
      const bool isLocal = (t < nLocal);
      const int tbase = wbase + t * 64;
      // ---- stage K (row-major) + V^T (swizzled) + gpos from prefetch regs ----
      *(bf16x8*)(&kT[p][skey][sd8]) = nk;
#pragma unroll
      for (int jj = 0; jj < 8; jj++) vT[p][sd8 + jj][vcol] = (u16)nv[jj];
      if (!isLocal && tid < 64) gposLds[p][tid] = ng;
      // ---- prefetch next tile (chained across supertile boundary) ----
      {
        const int nt = t + 1;
        const u16 *ksrc = nullptr, *vsrc = nullptr;
        if (nt < nLocal) {
          const u16* base = qkv + (size_t)(wbase + nt * 64 + skey) * QKV_STRIDE + hoff + sd8;
          ksrc = base + DIM; vsrc = base + 2 * DIM;
        } else if (nt < nTiles) {
          size_t grow = (size_t)((nt - nLocal) * 64 + skey) * DIM + hoff + sd8;
          ksrc = kg + grow; vsrc = vg + grow;
          if (tid < 64) ng = gidx[(nt - nLocal) * 64 + tid];
        } else if (sp == 0) {  // supertile B's tile 0 = window tile 0
          const u16* base = qkv + (size_t)(wbase + skey) * QKV_STRIDE + hoff + sd8;
          ksrc = base + DIM; vsrc = base + 2 * DIM;
        }
        if (ksrc) { nk = *(const bf16x8*)(ksrc); nv = *(const bf16x8*)(vsrc); }
      }
      __syncthreads();

      // fully-masked local tile for this wave -> skip compute
      if (isLocal && tbase > qwmax) continue;

      // ---- QK^T (swapped): S^T[key][q], K from LDS ----
      float sv[32];
      __builtin_amdgcn_s_setprio(1);
#pragma unroll
      for (int kb = 0; kb < 2; kb++) {
        const u16* krow = &kT[p][kb * 32 + l31][hi * 8];
        bf16x8 k0 = *(const bf16x8*)(krow);
        bf16x8 k1 = *(const bf16x8*)(krow + 16);
        bf16x8 k2 = *(const bf16x8*)(krow + 32);
        bf16x8 k3 = *(const bf16x8*)(krow + 48);
        f32x16 z = {};
        z = __builtin_amdgcn_mfma_f32_32x32x16_bf16(k0, qf[0], z, 0, 0, 0);
        z = __builtin_amdgcn_mfma_f32_32x32x16_bf16(k1, qf[1], z, 0, 0, 0);
        z = __builtin_amdgcn_mfma_f32_32x32x16_bf16(k2, qf[2], z, 0, 0, 0);
        z = __builtin_amdgcn_mfma_f32_32x32x16_bf16(k3, qf[3], z, 0, 0, 0);
#pragma unroll
        for (int r = 0; r < 16; r++) sv[kb * 16 + r] = z[r];
      }
      __builtin_amdgcn_s_setprio(0);

      // ---- causal mask (scale already folded into Q) ----
      if (isLocal) {
        const int lim = qrow - tbase;
        if (lim < 63) {
#pragma unroll
          for (int kb = 0; kb < 2; kb++)
#pragma unroll
            for (int r = 0; r < 16; r++) {
              int crow = kb * 32 + (r & 3) + 8 * (r >> 2) + 4 * hi;
              if (crow > lim) sv[kb * 16 + r] = -3.0e38f;
            }
        }
      } else {
#pragma unroll
        for (int kb = 0; kb < 2; kb++)
#pragma unroll
          for (int r = 0; r < 16; r++) {
            int kpos = gposLds[p][kb * 32 + (r & 3) + 8 * (r >> 2) + 4 * hi];
            if (kpos > qrow) sv[kb * 16 + r] = -3.0e38f;
          }
      }

      // ---- lane-local online softmax with defer-max ----
      float m0 = sv[0], m1 = sv[1], m2 = sv[2], m3 = sv[3];
#pragma unroll
      for (int i = 4; i < 32; i += 4) {
        m0 = fmaxf(m0, sv[i]);     m1 = fmaxf(m1, sv[i + 1]);
        m2 = fmaxf(m2, sv[i + 2]); m3 = fmaxf(m3, sv[i + 3]);
      }
      float vmax = fmaxf(fmaxf(m0, m1), fmaxf(m2, m3));
      vmax = fmaxf(vmax, __shfl_xor(vmax, 32));
      if (__any(vmax > mr + 11.0f)) {
        float mn = fmaxf(mr, vmax);
        float al = exp2f(mr - mn);
        lr *= al;
        mr = mn;
#pragma unroll
        for (int i = 0; i < 16; i++) { acc0[i] *= al; acc1[i] *= al; }
      }
      float s0 = 0.f, s1 = 0.f, s2 = 0.f, s3 = 0.f;
#pragma unroll
      for (int i = 0; i < 32; i += 4) {
        float p0 = exp2f(sv[i] - mr),     p1 = exp2f(sv[i + 1] - mr);
        float p2 = exp2f(sv[i + 2] - mr), p3 = exp2f(sv[i + 3] - mr);
        sv[i] = p0; sv[i + 1] = p1; sv[i + 2] = p2; sv[i + 3] = p3;
        s0 += p0; s1 += p1; s2 += p2; s3 += p3;
      }
      float ps = (s0 + s1) + (s2 + s3);
      ps += __shfl_xor(ps, 32);
      lr += ps;

      // ---- build P B-fragments in-register (cvt_pk + half-swap with lane^32) ----
      bf16x8 pf[4];
#pragma unroll
      for (int q4 = 0; q4 < 4; q4++) {
        int b = q4 * 8;
        uint32_t w0 = cvtpk(sv[b + 0], sv[b + 1]);
        uint32_t w1 = cvtpk(sv[b + 2], sv[b + 3]);
        uint32_t w2 = cvtpk(sv[b + 4], sv[b + 5]);
        uint32_t w3 = cvtpk(sv[b + 6], sv[b + 7]);
        uint32_t w0s = __shfl_xor((int)w0, 32), w2s = __shfl_xor((int)w2, 32);
        uint32_t w1s = __shfl_xor((int)w1, 32), w3s = __shfl_xor((int)w3, 32);
        union { uint32_t w[4]; bf16x8 v; } u;
        u.w[0] = hi ? w2s : w0;
        u.w[1] = hi ? w3s : w1;
        u.w[2] = hi ? w2 : w0s;
        u.w[3] = hi ? w3 : w1s;
        pf[q4] = u.v;
      }

      // ---- PV: O^T[d][q] = mfma(V^T, P) ----
      __builtin_amdgcn_s_setprio(1);
#pragma unroll
      for (int dblk = 0; dblk < 2; dblk++) {
        const int swz = (dblk * 2 + (l31 >> 4)) << 4;
        const u16* vrow = &vT[p][dblk * 32 + l31][0];
        f32x16 a = dblk ? acc1 : acc0;
#pragma unroll
        for (int ksg = 0; ksg < 4; ksg++) {
          bf16x8 vf = *(const bf16x8*)(vrow + ((ksg * 16 + hi * 8) ^ swz));
          a = __builtin_amdgcn_mfma_f32_32x32x16_bf16(vf, pf[ksg], a, 0, 0, 0);
        }
        if (dblk) acc1 = a; else acc0 = a;
      }
      __builtin_amdgcn_s_setprio(0);
    }

    // ---- normalize (lane-local) + store O for this supertile ----
    float inv = 1.0f / lr;
#pragma unroll
    for (int dblk = 0; dblk < 2; dblk++) {
      f32x16 a = dblk ? acc1 : acc0;
#pragma unroll
      for (int g = 0; g < 4; g++) {
        uint64_t pk = (uint64_t)f2bf(a[g * 4 + 0] * inv)
                    | ((uint64_t)f2bf(a[g * 4 + 1] * inv) << 16)
                    | ((uint64_t)f2bf(a[g * 4 + 2] * inv) << 32)
                    | ((uint64_t)f2bf(a[g * 4 + 3] * inv) << 48);
        *(uint64_t*)(o + (size_t)qrow * DIM + hoff + dblk * 32 + g * 8 + 4 * hi) = pk;
      }
    }
  }
}

// ---------------- launch ----------------
extern "C" void kernel_launch(void* const* d_in, const int* in_sizes, int n_in,
                              void* d_out, int out_size, void* d_ws, size_t ws_size,
                              hipStream_t stream) {
  const float* x  = (const float*)d_in[0];
  const float* nw = (const float*)d_in[1];
  const float* wq = (const float*)d_in[2];
  const float* wk = (const float*)d_in[3];
  const float* wv = (const float*)d_in[4];
  const float* wo = (const float*)d_in[5];
  const float* sw = (const float*)d_in[6];
  const float* sb = (const float*)d_in[7];
  float* out = (float*)d_out;

  char* ws = (char*)d_ws;
  size_t off = 0;
  auto alloc = [&](size_t b) {
    char* p = ws + off;
    off = (off + b + 255) & ~(size_t)255;
    return p;
  };
  u16*   h      = (u16*)alloc((size_t)S_LEN * DIM * 2);
  u16*   wqkvT  = (u16*)alloc((size_t)3 * DIM * DIM * 2);
  u16*   woutT  = (u16*)alloc((size_t)DIM * DIM * 2);
  u16*   qkv    = (u16*)alloc((size_t)S_LEN * 3 * DIM * 2);
  u16*   obuf   = (u16*)alloc((size_t)S_LEN * DIM * 2);
  float* scores = (float*)alloc((size_t)S_LEN * 4);
  int*   cnt    = (int*)alloc((size_t)S_LEN * 4);
  int*   gidx   = (int*)alloc((size_t)GTOK * 4);
  u16*   kgbuf  = (u16*)alloc((size_t)GTOK * DIM * 2);
  u16*   vgbuf  = (u16*)alloc((size_t)GTOK * DIM * 2);

  transpose_w_kernel<<<dim3(32, 32, 4), dim3(32, 8), 0, stream>>>(wq, wk, wv, wo, wqkvT, woutT);
  rmsnorm_score_kernel<<<dim3(S_LEN), dim3(256), 0, stream>>>(x, nw, sw, sb, h, scores, cnt);
  topk_count_kernel<<<dim3(32, 8), dim3(256), 0, stream>>>(scores, cnt);
  topk_scatter_kernel<<<dim3(S_LEN / 256), dim3(256), 0, stream>>>(cnt, gidx);
  gemm256_kernel<0><<<dim3(32, 24), dim3(512), 0, stream>>>(h, wqkvT, qkv, nullptr, nullptr,
                                                            S_LEN, 3 * DIM, DIM);
  gather_kernel<<<dim3(GTOK), dim3(128), 0, stream>>>(qkv, gidx, kgbuf, vgbuf);
  attn_kernel<<<dim3(16, NH), dim3(512), 0, stream>>>(qkv, kgbuf, vgbuf, gidx, obuf);
  gemm256_kernel<1><<<dim3(32, 8), dim3(512), 0, stream>>>(obuf, woutT, nullptr, out, x,
                                                           S_LEN, DIM, DIM);
}

// Round 13
// 219.207 us; speedup vs baseline: 1.3234x; 1.0027x over previous
//
#include <hip/hip_runtime.h>
#include <stdint.h>

#define S_LEN 8192
#define DIM   1024
#define NH    16
#define HD    64
#define WIN   1024
#define GTOK  256
#define QKV_STRIDE (3 * DIM)

typedef __attribute__((ext_vector_type(8))) short bf16x8;
typedef __attribute__((ext_vector_type(4))) float f32x4;
typedef __attribute__((ext_vector_type(16))) float f32x16;
typedef unsigned short u16;
typedef uint32_t u32;

__device__ __forceinline__ u16 f2bf(float f) {
  union { float f; uint32_t u; } v; v.f = f;
  uint32_t r = v.u + 0x7fffu + ((v.u >> 16) & 1u);
  return (u16)(r >> 16);
}
__device__ __forceinline__ float bf2f(u16 b) {
  union { uint32_t u; float f; } v; v.u = ((uint32_t)b) << 16;
  return v.f;
}
__device__ __forceinline__ uint32_t cvtpk(float a, float b) {
  uint32_t r;
  asm("v_cvt_pk_bf16_f32 %0, %1, %2" : "=v"(r) : "v"(a), "v"(b));
  return r;
}

__device__ __forceinline__ void gload_lds16(const void* g, void* l) {
  __builtin_amdgcn_global_load_lds((const __attribute__((address_space(1))) void*)g,
                                   (__attribute__((address_space(3))) void*)l, 16, 0, 0);
}

// ---------------- RMSNorm + scorer (+ cnt zeroing for topk) ----------------
__global__ __launch_bounds__(256) void rmsnorm_score_kernel(
    const float* __restrict__ x, const float* __restrict__ nw,
    const float* __restrict__ sw, const float* __restrict__ sb,
    u16* __restrict__ h, float* __restrict__ scores, int* __restrict__ cnt) {
  int row = blockIdx.x, tid = threadIdx.x;
  const float4* xr = (const float4*)(x + (size_t)row * DIM);
  float4 v = xr[tid];
  float ss = v.x * v.x + v.y * v.y + v.z * v.z + v.w * v.w;
#pragma unroll
  for (int o = 32; o >= 1; o >>= 1) ss += __shfl_xor(ss, o);
  __shared__ float red[4], red2[4];
  int wv = tid >> 6;
  if ((tid & 63) == 0) red[wv] = ss;
  __syncthreads();
  ss = red[0] + red[1] + red[2] + red[3];
  float rn = rsqrtf(ss * (1.0f / DIM) + 1e-6f);
  float4 w4 = ((const float4*)nw)[tid];
  float h0 = v.x * rn * w4.x, h1 = v.y * rn * w4.y;
  float h2 = v.z * rn * w4.z, h3 = v.w * rn * w4.w;
  uint64_t pack = (uint64_t)f2bf(h0) | ((uint64_t)f2bf(h1) << 16) |
                  ((uint64_t)f2bf(h2) << 32) | ((uint64_t)f2bf(h3) << 48);
  *(uint64_t*)(h + (size_t)row * DIM + tid * 4) = pack;
  float4 s4 = ((const float4*)sw)[tid];
  float sc = h0 * s4.x + h1 * s4.y + h2 * s4.z + h3 * s4.w;
#pragma unroll
  for (int o = 32; o >= 1; o >>= 1) sc += __shfl_xor(sc, o);
  if ((tid & 63) == 0) red2[wv] = sc;
  __syncthreads();
  if (tid == 0) {
    scores[row] = red2[0] + red2[1] + red2[2] + red2[3] + sb[0];
    cnt[row] = 0;
  }
}

// ---------------- weight transpose + bf16 convert ----------------
__global__ __launch_bounds__(256) void transpose_w_kernel(
    const float* __restrict__ wq, const float* __restrict__ wk,
    const float* __restrict__ wv, const float* __restrict__ wo,
    u16* __restrict__ wqkvT, u16* __restrict__ woutT) {
  __shared__ float tile[32][33];
  int z = blockIdx.z;
  const float* src = (z == 0) ? wq : (z == 1) ? wk : (z == 2) ? wv : wo;
  u16* dst = (z < 3) ? (wqkvT + (size_t)z * DIM * DIM) : woutT;
  int tx = threadIdx.x, ty = threadIdx.y;  // 32 x 8
  int n0 = blockIdx.x * 32, k0 = blockIdx.y * 32;
#pragma unroll
  for (int i = 0; i < 4; i++)
    tile[ty + i * 8][tx] = src[(size_t)(k0 + ty + i * 8) * DIM + n0 + tx];
  __syncthreads();
#pragma unroll
  for (int i = 0; i < 4; i++)
    dst[(size_t)(n0 + ty + i * 8) * DIM + k0 + tx] = f2bf(tile[tx][ty + i * 8]);
}

// ---------------- exact top-G by distributed rank counting ----------------
__global__ __launch_bounds__(256) void topk_count_kernel(
    const float* __restrict__ scores, int* __restrict__ cnt) {
  __shared__ float sj[1024];
  int jbase = blockIdx.y * 1024;
  for (int t = threadIdx.x; t < 1024; t += 256) sj[t] = scores[jbase + t];
  __syncthreads();
  int i = blockIdx.x * 256 + threadIdx.x;
  float my = scores[i];
  int c = 0;
  const float4* s4 = (const float4*)sj;
#pragma unroll 4
  for (int j = 0; j < 256; j++) {
    float4 v = s4[j];
    int b = jbase + j * 4;
    c += (v.x > my) || (v.x == my && (b + 0) < i);
    c += (v.y > my) || (v.y == my && (b + 1) < i);
    c += (v.z > my) || (v.z == my && (b + 2) < i);
    c += (v.w > my) || (v.w == my && (b + 3) < i);
  }
  if (c) atomicAdd(&cnt[i], c);
}

__global__ __launch_bounds__(256) void topk_scatter_kernel(
    const int* __restrict__ cnt, int* __restrict__ gidx) {
  int i = blockIdx.x * 256 + threadIdx.x;
  int c = cnt[i];
  if (c < GTOK) gidx[c] = i;
}

// ---------------- gather top-G K/V rows ----------------
__global__ __launch_bounds__(128) void gather_kernel(
    const u16* __restrict__ qkv, const int* __restrict__ gidx,
    u16* __restrict__ kg, u16* __restrict__ vg) {
  int g = blockIdx.x, t = threadIdx.x;
  size_t src = (size_t)gidx[g] * QKV_STRIDE;
  *(bf16x8*)(kg + (size_t)g * DIM + t * 8) = *(const bf16x8*)(qkv + src + DIM + t * 8);
  *(bf16x8*)(vg + (size_t)g * DIM + t * 8) = *(const bf16x8*)(qkv + src + 2 * DIM + t * 8);
}

// ---------------- GEMM 256Mx128N tile, 8 waves, BK=64, 3-buf 2-deep counted-vmcnt ----------------
// (round-8 exact version -- best measured GEMM)
template <int RESID>
__global__ __launch_bounds__(512, 2) void gemm256_kernel(
    const u16* __restrict__ A, const u16* __restrict__ B,
    u16* __restrict__ Cb, float* __restrict__ Cf, const float* __restrict__ X,
    int M, int N, int K) {
  __shared__ __align__(16) u16 As[3][256 * 64];
  __shared__ __align__(16) u16 Bs[3][128 * 64];
  const int tid = threadIdx.x;
  const int wave = tid >> 6, lane = tid & 63;
  const int l15 = lane & 15, l4 = lane >> 4;
  const int wr = wave >> 1, wc = wave & 1;  // 4M x 2N wave grid, 64x64 per wave
  const int mbase = blockIdx.x * 256, nbase = blockIdx.y * 128;
  const int srow = lane >> 3, schunk = lane & 7;
  const int gcol = (schunk ^ srow) * 8;

  auto stage = [&](int tt, int b) {
    const int kt = tt << 6;
#pragma unroll
    for (int q = 0; q < 4; q++) {
      int row = wave * 32 + q * 8;
      gload_lds16(A + (size_t)(mbase + row + srow) * K + kt + gcol, &As[b][row * 64]);
    }
#pragma unroll
    for (int q = 0; q < 2; q++) {
      int row = wave * 16 + q * 8;
      gload_lds16(B + (size_t)(nbase + row + srow) * K + kt + gcol, &Bs[b][row * 64]);
    }
  };

  const int nt = K >> 6;
  f32x4 acc[4][4] = {};

  stage(0, 0);
  stage(1, 1);
  asm volatile("s_waitcnt vmcnt(6)" ::: "memory");
  __builtin_amdgcn_s_barrier();
  __builtin_amdgcn_sched_barrier(0);

  int cur = 0;
  for (int t = 0; t < nt; t++) {
    int pre = cur + 2; if (pre >= 3) pre -= 3;
    if (t + 2 < nt) stage(t + 2, pre);
    const u16* Ab = &As[cur][0];
    const u16* Bb = &Bs[cur][0];
    bf16x8 bfr[4][2], af[4][2];
#pragma unroll
    for (int nf = 0; nf < 4; nf++) {
      int row = wc * 64 + nf * 16 + l15;
#pragma unroll
      for (int kk = 0; kk < 2; kk++)
        bfr[nf][kk] = *(const bf16x8*)(Bb + row * 64 + (((kk * 4 + l4) ^ (l15 & 7)) * 8));
    }
#pragma unroll
    for (int mi = 0; mi < 4; mi++) {
      int row = wr * 64 + mi * 16 + l15;
#pragma unroll
      for (int kk = 0; kk < 2; kk++)
        af[mi][kk] = *(const bf16x8*)(Ab + row * 64 + (((kk * 4 + l4) ^ (l15 & 7)) * 8));
    }
    __builtin_amdgcn_s_setprio(1);
#pragma unroll
    for (int mi = 0; mi < 4; mi++)
#pragma unroll
      for (int nf = 0; nf < 4; nf++)
#pragma unroll
        for (int kk = 0; kk < 2; kk++)
          acc[mi][nf] = __builtin_amdgcn_mfma_f32_16x16x32_bf16(af[mi][kk], bfr[nf][kk],
                                                                acc[mi][nf], 0, 0, 0);
    __builtin_amdgcn_s_setprio(0);
    if (t + 1 < nt) {
      if (t + 2 < nt) asm volatile("s_waitcnt vmcnt(6)" ::: "memory");
      else            asm volatile("s_waitcnt vmcnt(0)" ::: "memory");
      __builtin_amdgcn_s_barrier();
      __builtin_amdgcn_sched_barrier(0);
    }
    cur = (cur + 1 == 3) ? 0 : cur + 1;
  }

#pragma unroll
  for (int mi = 0; mi < 4; mi++) {
#pragma unroll
    for (int nf = 0; nf < 4; nf++) {
#pragma unroll
      for (int r = 0; r < 4; r++) {
        int row = mbase + wr * 64 + mi * 16 + l4 * 4 + r;
        int col = nbase + wc * 64 + nf * 16 + l15;
        float v = acc[mi][nf][r];
        if (RESID) Cf[(size_t)row * N + col] = X[(size_t)row * N + col] + v;
        else       Cb[(size_t)row * N + col] = f2bf(v);
      }
    }
  }
}

// ---------------- fused flash attention v10: cross-supertile K/V time-share ----------------
// Block = 8 waves; holds TWO supertiles' state (A=j, B=3-j) in registers and runs ONE
// tile loop over the union of their KV tiles (nLocB local + 4 global). Each staged tile
// is computed by stream A then stream B between the same barriers: staging/barrier
// rounds 28->20/16, and two independent dep chains per interval (MFMA||VALU overlap).
__global__ __launch_bounds__(512) void attn_kernel(
    const u16* __restrict__ qkv, const u16* __restrict__ kg,
    const u16* __restrict__ vg, const int* __restrict__ gidx,
    u16* __restrict__ o) {
  __shared__ u16 kT[2][64][72];   // [buf][key][d] (+8 pad)
  __shared__ u16 vT[2][64][72];   // [buf][d][key^((d>>4)<<4)]
  __shared__ int gposLds[2][64];
  const int tid = threadIdx.x, wave = tid >> 6, lane = tid & 63;
  const int l31 = lane & 31, hi = lane >> 5;
  const int win = blockIdx.x >> 1, pair = blockIdx.x & 1;
  const int wbase = win * WIN;
  const int hoff = blockIdx.y * HD;

  const int jA = pair, jB = 3 - pair;          // jB > jA
  const int qsA = wbase + jA * 256, qsB = wbase + jB * 256;
  const int nLocB = (jB + 1) * 4;              // union local tile count
  const int nTiles = nLocB + GTOK / 64;
  const int qrowA = qsA + wave * 32 + l31, qwmaxA = qsA + wave * 32 + 31;
  const int qrowB = qsB + wave * 32 + l31, qwmaxB = qsB + wave * 32 + 31;

  // staging map: thread covers key=skey, dims sd8..sd8+7 (16 B of K and of V)
  const int skey = tid >> 3, sd8 = (tid & 7) * 8;
  const int vcol = skey ^ ((sd8 >> 4) << 4);

  // Q B-fragments for both streams, scale*log2e folded in
  bf16x8 qfA[4], qfB[4];
  {
    const float SC2 = 0.125f * 1.44269504088896f;
    const u16* qpA = qkv + (size_t)qrowA * QKV_STRIDE + hoff + hi * 8;
    const u16* qpB = qkv + (size_t)qrowB * QKV_STRIDE + hoff + hi * 8;
#pragma unroll
    for (int ks = 0; ks < 4; ks++) {
      bf16x8 ra = *(const bf16x8*)(qpA + ks * 16);
      bf16x8 rb = *(const bf16x8*)(qpB + ks * 16);
      bf16x8 sa, sb2;
#pragma unroll
      for (int jj = 0; jj < 8; jj++) {
        sa[jj]  = (short)f2bf(bf2f((u16)ra[jj]) * SC2);
        sb2[jj] = (short)f2bf(bf2f((u16)rb[jj]) * SC2);
      }
      qfA[ks] = sa;
      qfB[ks] = sb2;
    }
  }

  // prologue prefetch: window tile 0
  bf16x8 nk, nv;
  int ng = 0;
  {
    const u16* base = qkv + (size_t)(wbase + skey) * QKV_STRIDE + hoff + sd8;
    nk = *(const bf16x8*)(base + DIM);
    nv = *(const bf16x8*)(base + 2 * DIM);
  }

  f32x16 accA0 = {}, accA1 = {}, accB0 = {}, accB1 = {};
  float mrA = -3.0e38f, lrA = 0.f, mrB = -3.0e38f, lrB = 0.f;

  // per-stream tile compute (QK -> mask -> online softmax -> pack -> PV)
  auto computeStream = [&](const bf16x8* qf, f32x16& a0, f32x16& a1,
                           float& mr, float& lr, int qrow,
                           bool isLocal, int tbase, int p) {
    float sv[32];
    __builtin_amdgcn_s_setprio(1);
#pragma unroll
    for (int kb = 0; kb < 2; kb++) {
      const u16* krow = &kT[p][kb * 32 + l31][hi * 8];
      bf16x8 k0 = *(const bf16x8*)(krow);
      bf16x8 k1 = *(const bf16x8*)(krow + 16);
      bf16x8 k2 = *(const bf16x8*)(krow + 32);
      bf16x8 k3 = *(const bf16x8*)(krow + 48);
      f32x16 z = {};
      z = __builtin_amdgcn_mfma_f32_32x32x16_bf16(k0, qf[0], z, 0, 0, 0);
      z = __builtin_amdgcn_mfma_f32_32x32x16_bf16(k1, qf[1], z, 0, 0, 0);
      z = __builtin_amdgcn_mfma_f32_32x32x16_bf16(k2, qf[2], z, 0, 0, 0);
      z = __builtin_amdgcn_mfma_f32_32x32x16_bf16(k3, qf[3], z, 0, 0, 0);
#pragma unroll
      for (int r = 0; r < 16; r++) sv[kb * 16 + r] = z[r];
    }
    __builtin_amdgcn_s_setprio(0);

    if (isLocal) {
      const int lim = qrow - tbase;
      if (lim < 63) {
#pragma unroll
        for (int kb = 0; kb < 2; kb++)
#pragma unroll
          for (int r = 0; r < 16; r++) {
            int crow = kb * 32 + (r & 3) + 8 * (r >> 2) + 4 * hi;
            if (crow > lim) sv[kb * 16 + r] = -3.0e38f;
          }
      }
    } else {
#pragma unroll
      for (int kb = 0; kb < 2; kb++)
#pragma unroll
        for (int r = 0; r < 16; r++) {
          int kpos = gposLds[p][kb * 32 + (r & 3) + 8 * (r >> 2) + 4 * hi];
          if (kpos > qrow) sv[kb * 16 + r] = -3.0e38f;
        }
    }

    float m0 = sv[0], m1 = sv[1], m2 = sv[2], m3 = sv[3];
#pragma unroll
    for (int i = 4; i < 32; i += 4) {
      m0 = fmaxf(m0, sv[i]);     m1 = fmaxf(m1, sv[i + 1]);
      m2 = fmaxf(m2, sv[i + 2]); m3 = fmaxf(m3, sv[i + 3]);
    }
    float vmax = fmaxf(fmaxf(m0, m1), fmaxf(m2, m3));
    vmax = fmaxf(vmax, __shfl_xor(vmax, 32));
    if (__any(vmax > mr + 11.0f)) {
      float mn = fmaxf(mr, vmax);
      float al = exp2f(mr - mn);
      lr *= al;
      mr = mn;
#pragma unroll
      for (int i = 0; i < 16; i++) { a0[i] *= al; a1[i] *= al; }
    }
    float s0 = 0.f, s1 = 0.f, s2 = 0.f, s3 = 0.f;
#pragma unroll
    for (int i = 0; i < 32; i += 4) {
      float p0 = exp2f(sv[i] - mr),     p1 = exp2f(sv[i + 1] - mr);
      float p2 = exp2f(sv[i + 2] - mr), p3 = exp2f(sv[i + 3] - mr);
      sv[i] = p0; sv[i + 1] = p1; sv[i + 2] = p2; sv[i + 3] = p3;
      s0 += p0; s1 += p1; s2 += p2; s3 += p3;
    }
    float ps = (s0 + s1) + (s2 + s3);
    ps += __shfl_xor(ps, 32);
    lr += ps;

    bf16x8 pf[4];
#pragma unroll
    for (int q4 = 0; q4 < 4; q4++) {
      int b = q4 * 8;
      uint32_t w0 = cvtpk(sv[b + 0], sv[b + 1]);
      uint32_t w1 = cvtpk(sv[b + 2], sv[b + 3]);
      uint32_t w2 = cvtpk(sv[b + 4], sv[b + 5]);
      uint32_t w3 = cvtpk(sv[b + 6], sv[b + 7]);
      uint32_t w0s = __shfl_xor((int)w0, 32), w2s = __shfl_xor((int)w2, 32);
      uint32_t w1s = __shfl_xor((int)w1, 32), w3s = __shfl_xor((int)w3, 32);
      union { uint32_t w[4]; bf16x8 v; } u;
      u.w[0] = hi ? w2s : w0;
      u.w[1] = hi ? w3s : w1;
      u.w[2] = hi ? w2 : w0s;
      u.w[3] = hi ? w3 : w1s;
      pf[q4] = u.v;
    }

    __builtin_amdgcn_s_setprio(1);
#pragma unroll
    for (int dblk = 0; dblk < 2; dblk++) {
      const int swz = (dblk * 2 + (l31 >> 4)) << 4;
      const u16* vrow = &vT[p][dblk * 32 + l31][0];
      f32x16 a = dblk ? a1 : a0;
#pragma unroll
      for (int ksg = 0; ksg < 4; ksg++) {
        bf16x8 vf = *(const bf16x8*)(vrow + ((ksg * 16 + hi * 8) ^ swz));
        a = __builtin_amdgcn_mfma_f32_32x32x16_bf16(vf, pf[ksg], a, 0, 0, 0);
      }
      if (dblk) a1 = a; else a0 = a;
    }
    __builtin_amdgcn_s_setprio(0);
  };

  for (int t = 0; t < nTiles; t++) {
    const int p = t & 1;
    const bool isLocal = (t < nLocB);
    const int tbase = wbase + t * 64;
    // ---- stage K (row-major) + V^T (swizzled) + gpos from prefetch regs ----
    *(bf16x8*)(&kT[p][skey][sd8]) = nk;
#pragma unroll
    for (int jj = 0; jj < 8; jj++) vT[p][sd8 + jj][vcol] = (u16)nv[jj];
    if (!isLocal && tid < 64) gposLds[p][tid] = ng;
    // ---- prefetch next tile ----
    {
      const int nt = t + 1;
      const u16 *ksrc = nullptr, *vsrc = nullptr;
      if (nt < nLocB) {
        const u16* base = qkv + (size_t)(wbase + nt * 64 + skey) * QKV_STRIDE + hoff + sd8;
        ksrc = base + DIM; vsrc = base + 2 * DIM;
      } else if (nt < nTiles) {
        size_t grow = (size_t)((nt - nLocB) * 64 + skey) * DIM + hoff + sd8;
        ksrc = kg + grow; vsrc = vg + grow;
        if (tid < 64) ng = gidx[(nt - nLocB) * 64 + tid];
      }
      if (ksrc) { nk = *(const bf16x8*)(ksrc); nv = *(const bf16x8*)(vsrc); }
    }
    __syncthreads();

    // stream A: local tiles beyond A's causal reach auto-skip (tbase > qwmaxA)
    if (!(isLocal && tbase > qwmaxA))
      computeStream(qfA, accA0, accA1, mrA, lrA, qrowA, isLocal, tbase, p);
    // stream B
    if (!(isLocal && tbase > qwmaxB))
      computeStream(qfB, accB0, accB1, mrB, lrB, qrowB, isLocal, tbase, p);
  }

  // ---- normalize (lane-local) + store O for both supertiles ----
  float invA = 1.0f / lrA, invB = 1.0f / lrB;
#pragma unroll
  for (int dblk = 0; dblk < 2; dblk++) {
    f32x16 a = dblk ? accA1 : accA0;
    f32x16 b = dblk ? accB1 : accB0;
#pragma unroll
    for (int g = 0; g < 4; g++) {
      uint64_t pkA = (uint64_t)f2bf(a[g * 4 + 0] * invA)
                   | ((uint64_t)f2bf(a[g * 4 + 1] * invA) << 16)
                   | ((uint64_t)f2bf(a[g * 4 + 2] * invA) << 32)
                   | ((uint64_t)f2bf(a[g * 4 + 3] * invA) << 48);
      *(uint64_t*)(o + (size_t)qrowA * DIM + hoff + dblk * 32 + g * 8 + 4 * hi) = pkA;
      uint64_t pkB = (uint64_t)f2bf(b[g * 4 + 0] * invB)
                   | ((uint64_t)f2bf(b[g * 4 + 1] * invB) << 16)
                   | ((uint64_t)f2bf(b[g * 4 + 2] * invB) << 32)
                   | ((uint64_t)f2bf(b[g * 4 + 3] * invB) << 48);
      *(uint64_t*)(o + (size_t)qrowB * DIM + hoff + dblk * 32 + g * 8 + 4 * hi) = pkB;
    }
  }
}

// ---------------- launch ----------------
extern "C" void kernel_launch(void* const* d_in, const int* in_sizes, int n_in,
                              void* d_out, int out_size, void* d_ws, size_t ws_size,
                              hipStream_t stream) {
  const float* x  = (const float*)d_in[0];
  const float* nw = (const float*)d_in[1];
  const float* wq = (const float*)d_in[2];
  const float* wk = (const float*)d_in[3];
  const float* wv = (const float*)d_in[4];
  const float* wo = (const float*)d_in[5];
  const float* sw = (const float*)d_in[6];
  const float* sb = (const float*)d_in[7];
  float* out = (float*)d_out;

  char* ws = (char*)d_ws;
  size_t off = 0;
  auto alloc = [&](size_t b) {
    char* p = ws + off;
    off = (off + b + 255) & ~(size_t)255;
    return p;
  };
  u16*   h      = (u16*)alloc((size_t)S_LEN * DIM * 2);
  u16*   wqkvT  = (u16*)alloc((size_t)3 * DIM * DIM * 2);
  u16*   woutT  = (u16*)alloc((size_t)DIM * DIM * 2);
  u16*   qkv    = (u16*)alloc((size_t)S_LEN * 3 * DIM * 2);
  u16*   obuf   = (u16*)alloc((size_t)S_LEN * DIM * 2);
  float* scores = (float*)alloc((size_t)S_LEN * 4);
  int*   cnt    = (int*)alloc((size_t)S_LEN * 4);
  int*   gidx   = (int*)alloc((size_t)GTOK * 4);
  u16*   kgbuf  = (u16*)alloc((size_t)GTOK * DIM * 2);
  u16*   vgbuf  = (u16*)alloc((size_t)GTOK * DIM * 2);

  transpose_w_kernel<<<dim3(32, 32, 4), dim3(32, 8), 0, stream>>>(wq, wk, wv, wo, wqkvT, woutT);
  rmsnorm_score_kernel<<<dim3(S_LEN), dim3(256), 0, stream>>>(x, nw, sw, sb, h, scores, cnt);
  topk_count_kernel<<<dim3(32, 8), dim3(256), 0, stream>>>(scores, cnt);
  topk_scatter_kernel<<<dim3(S_LEN / 256), dim3(256), 0, stream>>>(cnt, gidx);
  gemm256_kernel<0><<<dim3(32, 24), dim3(512), 0, stream>>>(h, wqkvT, qkv, nullptr, nullptr,
                                                            S_LEN, 3 * DIM, DIM);
  gather_kernel<<<dim3(GTOK), dim3(128), 0, stream>>>(qkv, gidx, kgbuf, vgbuf);
  attn_kernel<<<dim3(16, NH), dim3(512), 0, stream>>>(qkv, kgbuf, vgbuf, gidx, obuf);
  gemm256_kernel<1><<<dim3(32, 8), dim3(512), 0, stream>>>(obuf, woutT, nullptr, out, x,
                                                           S_LEN, DIM, DIM);
}

// Round 14
// 215.254 us; speedup vs baseline: 1.3477x; 1.0184x over previous
//
#include <hip/hip_runtime.h>
#include <stdint.h>

#define S_LEN 8192
#define DIM   1024
#define NH    16
#define HD    64
#define WIN   1024
#define GTOK  256
#define QKV_STRIDE (3 * DIM)

typedef __attribute__((ext_vector_type(8))) short bf16x8;
typedef __attribute__((ext_vector_type(4))) float f32x4;
typedef __attribute__((ext_vector_type(16))) float f32x16;
typedef unsigned short u16;
typedef uint32_t u32;

__device__ __forceinline__ u16 f2bf(float f) {
  union { float f; uint32_t u; } v; v.f = f;
  uint32_t r = v.u + 0x7fffu + ((v.u >> 16) & 1u);
  return (u16)(r >> 16);
}
__device__ __forceinline__ float bf2f(u16 b) {
  union { uint32_t u; float f; } v; v.u = ((uint32_t)b) << 16;
  return v.f;
}
__device__ __forceinline__ uint32_t cvtpk(float a, float b) {
  uint32_t r;
  asm("v_cvt_pk_bf16_f32 %0, %1, %2" : "=v"(r) : "v"(a), "v"(b));
  return r;
}

__device__ __forceinline__ void gload_lds16(const void* g, void* l) {
  __builtin_amdgcn_global_load_lds((const __attribute__((address_space(1))) void*)g,
                                   (__attribute__((address_space(3))) void*)l, 16, 0, 0);
}

// ---------------- RMSNorm + scorer (+ cnt zeroing for topk) ----------------
__global__ __launch_bounds__(256) void rmsnorm_score_kernel(
    const float* __restrict__ x, const float* __restrict__ nw,
    const float* __restrict__ sw, const float* __restrict__ sb,
    u16* __restrict__ h, float* __restrict__ scores, int* __restrict__ cnt) {
  int row = blockIdx.x, tid = threadIdx.x;
  const float4* xr = (const float4*)(x + (size_t)row * DIM);
  float4 v = xr[tid];
  float ss = v.x * v.x + v.y * v.y + v.z * v.z + v.w * v.w;
#pragma unroll
  for (int o = 32; o >= 1; o >>= 1) ss += __shfl_xor(ss, o);
  __shared__ float red[4], red2[4];
  int wv = tid >> 6;
  if ((tid & 63) == 0) red[wv] = ss;
  __syncthreads();
  ss = red[0] + red[1] + red[2] + red[3];
  float rn = rsqrtf(ss * (1.0f / DIM) + 1e-6f);
  float4 w4 = ((const float4*)nw)[tid];
  float h0 = v.x * rn * w4.x, h1 = v.y * rn * w4.y;
  float h2 = v.z * rn * w4.z, h3 = v.w * rn * w4.w;
  uint64_t pack = (uint64_t)f2bf(h0) | ((uint64_t)f2bf(h1) << 16) |
                  ((uint64_t)f2bf(h2) << 32) | ((uint64_t)f2bf(h3) << 48);
  *(uint64_t*)(h + (size_t)row * DIM + tid * 4) = pack;
  float4 s4 = ((const float4*)sw)[tid];
  float sc = h0 * s4.x + h1 * s4.y + h2 * s4.z + h3 * s4.w;
#pragma unroll
  for (int o = 32; o >= 1; o >>= 1) sc += __shfl_xor(sc, o);
  if ((tid & 63) == 0) red2[wv] = sc;
  __syncthreads();
  if (tid == 0) {
    scores[row] = red2[0] + red2[1] + red2[2] + red2[3] + sb[0];
    cnt[row] = 0;
  }
}

// ---------------- weight transpose + bf16 convert ----------------
__global__ __launch_bounds__(256) void transpose_w_kernel(
    const float* __restrict__ wq, const float* __restrict__ wk,
    const float* __restrict__ wv, const float* __restrict__ wo,
    u16* __restrict__ wqkvT, u16* __restrict__ woutT) {
  __shared__ float tile[32][33];
  int z = blockIdx.z;
  const float* src = (z == 0) ? wq : (z == 1) ? wk : (z == 2) ? wv : wo;
  u16* dst = (z < 3) ? (wqkvT + (size_t)z * DIM * DIM) : woutT;
  int tx = threadIdx.x, ty = threadIdx.y;  // 32 x 8
  int n0 = blockIdx.x * 32, k0 = blockIdx.y * 32;
#pragma unroll
  for (int i = 0; i < 4; i++)
    tile[ty + i * 8][tx] = src[(size_t)(k0 + ty + i * 8) * DIM + n0 + tx];
  __syncthreads();
#pragma unroll
  for (int i = 0; i < 4; i++)
    dst[(size_t)(n0 + ty + i * 8) * DIM + k0 + tx] = f2bf(tile[tx][ty + i * 8]);
}

// ---------------- exact top-G by distributed rank counting ----------------
__global__ __launch_bounds__(256) void topk_count_kernel(
    const float* __restrict__ scores, int* __restrict__ cnt) {
  __shared__ float sj[1024];
  int jbase = blockIdx.y * 1024;
  for (int t = threadIdx.x; t < 1024; t += 256) sj[t] = scores[jbase + t];
  __syncthreads();
  int i = blockIdx.x * 256 + threadIdx.x;
  float my = scores[i];
  int c = 0;
  const float4* s4 = (const float4*)sj;
#pragma unroll 4
  for (int j = 0; j < 256; j++) {
    float4 v = s4[j];
    int b = jbase + j * 4;
    c += (v.x > my) || (v.x == my && (b + 0) < i);
    c += (v.y > my) || (v.y == my && (b + 1) < i);
    c += (v.z > my) || (v.z == my && (b + 2) < i);
    c += (v.w > my) || (v.w == my && (b + 3) < i);
  }
  if (c) atomicAdd(&cnt[i], c);
}

__global__ __launch_bounds__(256) void topk_scatter_kernel(
    const int* __restrict__ cnt, int* __restrict__ gidx) {
  int i = blockIdx.x * 256 + threadIdx.x;
  int c = cnt[i];
  if (c < GTOK) gidx[c] = i;
}

// ---------------- gather top-G K/V rows ----------------
__global__ __launch_bounds__(128) void gather_kernel(
    const u16* __restrict__ qkv, const int* __restrict__ gidx,
    u16* __restrict__ kg, u16* __restrict__ vg) {
  int g = blockIdx.x, t = threadIdx.x;
  size_t src = (size_t)gidx[g] * QKV_STRIDE;
  *(bf16x8*)(kg + (size_t)g * DIM + t * 8) = *(const bf16x8*)(qkv + src + DIM + t * 8);
  *(bf16x8*)(vg + (size_t)g * DIM + t * 8) = *(const bf16x8*)(qkv + src + 2 * DIM + t * 8);
}

// ---------------- GEMM 256Mx128N tile, 8 waves, BK=64, 3-buf 2-deep counted-vmcnt ----------------
// (round-8 exact version -- best measured GEMM)
template <int RESID>
__global__ __launch_bounds__(512, 2) void gemm256_kernel(
    const u16* __restrict__ A, const u16* __restrict__ B,
    u16* __restrict__ Cb, float* __restrict__ Cf, const float* __restrict__ X,
    int M, int N, int K) {
  __shared__ __align__(16) u16 As[3][256 * 64];
  __shared__ __align__(16) u16 Bs[3][128 * 64];
  const int tid = threadIdx.x;
  const int wave = tid >> 6, lane = tid & 63;
  const int l15 = lane & 15, l4 = lane >> 4;
  const int wr = wave >> 1, wc = wave & 1;  // 4M x 2N wave grid, 64x64 per wave
  const int mbase = blockIdx.x * 256, nbase = blockIdx.y * 128;
  const int srow = lane >> 3, schunk = lane & 7;
  const int gcol = (schunk ^ srow) * 8;

  auto stage = [&](int tt, int b) {
    const int kt = tt << 6;
#pragma unroll
    for (int q = 0; q < 4; q++) {
      int row = wave * 32 + q * 8;
      gload_lds16(A + (size_t)(mbase + row + srow) * K + kt + gcol, &As[b][row * 64]);
    }
#pragma unroll
    for (int q = 0; q < 2; q++) {
      int row = wave * 16 + q * 8;
      gload_lds16(B + (size_t)(nbase + row + srow) * K + kt + gcol, &Bs[b][row * 64]);
    }
  };

  const int nt = K >> 6;
  f32x4 acc[4][4] = {};

  stage(0, 0);
  stage(1, 1);
  asm volatile("s_waitcnt vmcnt(6)" ::: "memory");
  __builtin_amdgcn_s_barrier();
  __builtin_amdgcn_sched_barrier(0);

  int cur = 0;
  for (int t = 0; t < nt; t++) {
    int pre = cur + 2; if (pre >= 3) pre -= 3;
    if (t + 2 < nt) stage(t + 2, pre);
    const u16* Ab = &As[cur][0];
    const u16* Bb = &Bs[cur][0];
    bf16x8 bfr[4][2], af[4][2];
#pragma unroll
    for (int nf = 0; nf < 4; nf++) {
      int row = wc * 64 + nf * 16 + l15;
#pragma unroll
      for (int kk = 0; kk < 2; kk++)
        bfr[nf][kk] = *(const bf16x8*)(Bb + row * 64 + (((kk * 4 + l4) ^ (l15 & 7)) * 8));
    }
#pragma unroll
    for (int mi = 0; mi < 4; mi++) {
      int row = wr * 64 + mi * 16 + l15;
#pragma unroll
      for (int kk = 0; kk < 2; kk++)
        af[mi][kk] = *(const bf16x8*)(Ab + row * 64 + (((kk * 4 + l4) ^ (l15 & 7)) * 8));
    }
    __builtin_amdgcn_s_setprio(1);
#pragma unroll
    for (int mi = 0; mi < 4; mi++)
#pragma unroll
      for (int nf = 0; nf < 4; nf++)
#pragma unroll
        for (int kk = 0; kk < 2; kk++)
          acc[mi][nf] = __builtin_amdgcn_mfma_f32_16x16x32_bf16(af[mi][kk], bfr[nf][kk],
                                                                acc[mi][nf], 0, 0, 0);
    __builtin_amdgcn_s_setprio(0);
    if (t + 1 < nt) {
      if (t + 2 < nt) asm volatile("s_waitcnt vmcnt(6)" ::: "memory");
      else            asm volatile("s_waitcnt vmcnt(0)" ::: "memory");
      __builtin_amdgcn_s_barrier();
      __builtin_amdgcn_sched_barrier(0);
    }
    cur = (cur + 1 == 3) ? 0 : cur + 1;
  }

#pragma unroll
  for (int mi = 0; mi < 4; mi++) {
#pragma unroll
    for (int nf = 0; nf < 4; nf++) {
#pragma unroll
      for (int r = 0; r < 4; r++) {
        int row = mbase + wr * 64 + mi * 16 + l4 * 4 + r;
        int col = nbase + wc * 64 + nf * 16 + l15;
        float v = acc[mi][nf][r];
        if (RESID) Cf[(size_t)row * N + col] = X[(size_t)row * N + col] + v;
        else       Cb[(size_t)row * N + col] = f2bf(v);
      }
    }
  }
}

// ---------------- fused flash attention v11: r12 structure + KVBLK=128 ----------------
// Block = 8 waves x 32 q = 256 q supertile; processes supertiles {pair, 3-pair}
// sequentially. Each barrier round stages 128 keys (double r12) and computes two
// 64-key sub-tiles -> barrier rounds 28 -> 14. pad-72 kT, XOR-16 vT per 64-half.
__global__ __launch_bounds__(512) void attn_kernel(
    const u16* __restrict__ qkv, const u16* __restrict__ kg,
    const u16* __restrict__ vg, const int* __restrict__ gidx,
    u16* __restrict__ o) {
  __shared__ u16 kT[2][128][72];   // [buf][key][d] (+8 pad)
  __shared__ u16 vT[2][64][136];   // [buf][d][key-halfXOR] (+8 pad)
  __shared__ int gposLds[2][128];
  const int tid = threadIdx.x, wave = tid >> 6, lane = tid & 63;
  const int l31 = lane & 31, hi = lane >> 5;
  const int win = blockIdx.x >> 1, pair = blockIdx.x & 1;
  const int wbase = win * WIN;
  const int hoff = blockIdx.y * HD;

  // staging map: thread covers keys {skey, skey+64}, dims sd8..sd8+7
  const int skey = tid >> 3, sd8 = (tid & 7) * 8;
  const int vcol = skey ^ ((sd8 >> 4) << 4);   // within 64-key half; half1 = +64

  // prologue prefetch: window tile 0 (128 keys)
  bf16x8 nk0, nk1, nv0, nv1;
  int ng = 0;
  {
    const u16* b0 = qkv + (size_t)(wbase + skey) * QKV_STRIDE + hoff + sd8;
    const u16* b1 = qkv + (size_t)(wbase + 64 + skey) * QKV_STRIDE + hoff + sd8;
    nk0 = *(const bf16x8*)(b0 + DIM);     nv0 = *(const bf16x8*)(b0 + 2 * DIM);
    nk1 = *(const bf16x8*)(b1 + DIM);     nv1 = *(const bf16x8*)(b1 + 2 * DIM);
  }

  for (int sp = 0; sp < 2; sp++) {
    const int j = sp ? (3 - pair) : pair;          // supertile index in window
    const int qsbase = wbase + j * 256;
    const int nLocal = (j + 1) * 2;                // 128-key tiles
    const int nTiles = nLocal + GTOK / 128;        // + 2 global tiles
    const int qrow = qsbase + wave * 32 + l31;
    const int qwmax = qsbase + wave * 32 + 31;

    // Q B-fragments with scale*log2e folded in
    bf16x8 qf[4];
    {
      const float SC2 = 0.125f * 1.44269504088896f;
      const u16* qptr = qkv + (size_t)qrow * QKV_STRIDE + hoff + hi * 8;
#pragma unroll
      for (int ks = 0; ks < 4; ks++) {
        bf16x8 raw = *(const bf16x8*)(qptr + ks * 16);
        bf16x8 sc;
#pragma unroll
        for (int jj = 0; jj < 8; jj++) sc[jj] = (short)f2bf(bf2f((u16)raw[jj]) * SC2);
        qf[ks] = sc;
      }
    }

    f32x16 acc0 = {}, acc1 = {};
    float mr = -3.0e38f, lr = 0.f;

    __syncthreads();  // all waves done with LDS buffers from previous supertile

    for (int t = 0; t < nTiles; t++) {
      const int p = t & 1;
      const bool isLocal = (t < nLocal);
      // ---- stage 128 keys: K (row-major) + V^T (swizzled) + gpos ----
      *(bf16x8*)(&kT[p][skey][sd8]) = nk0;
      *(bf16x8*)(&kT[p][64 + skey][sd8]) = nk1;
#pragma unroll
      for (int jj = 0; jj < 8; jj++) {
        vT[p][sd8 + jj][vcol] = (u16)nv0[jj];
        vT[p][sd8 + jj][64 + vcol] = (u16)nv1[jj];
      }
      if (!isLocal && tid < 128) gposLds[p][tid] = ng;
      // ---- prefetch next tile (chained across supertile boundary) ----
      {
        const int nt = t + 1;
        const u16 *k0s = nullptr, *k1s = nullptr, *v0s = nullptr, *v1s = nullptr;
        if (nt < nLocal) {
          const u16* b0 = qkv + (size_t)(wbase + nt * 128 + skey) * QKV_STRIDE + hoff + sd8;
          const u16* b1 = b0 + (size_t)64 * QKV_STRIDE;
          k0s = b0 + DIM; v0s = b0 + 2 * DIM;
          k1s = b1 + DIM; v1s = b1 + 2 * DIM;
        } else if (nt < nTiles) {
          size_t g0 = (size_t)((nt - nLocal) * 128 + skey) * DIM + hoff + sd8;
          k0s = kg + g0; v0s = vg + g0;
          k1s = kg + g0 + (size_t)64 * DIM; v1s = vg + g0 + (size_t)64 * DIM;
          if (tid < 128) ng = gidx[(nt - nLocal) * 128 + tid];
        } else if (sp == 0) {  // supertile B's tile 0 = window tile 0
          const u16* b0 = qkv + (size_t)(wbase + skey) * QKV_STRIDE + hoff + sd8;
          const u16* b1 = b0 + (size_t)64 * QKV_STRIDE;
          k0s = b0 + DIM; v0s = b0 + 2 * DIM;
          k1s = b1 + DIM; v1s = b1 + 2 * DIM;
        }
        if (k0s) {
          nk0 = *(const bf16x8*)(k0s); nv0 = *(const bf16x8*)(v0s);
          nk1 = *(const bf16x8*)(k1s); nv1 = *(const bf16x8*)(v1s);
        }
      }
      __syncthreads();

#pragma unroll
      for (int sub = 0; sub < 2; sub++) {
        const int tbase = wbase + t * 128 + sub * 64;
        if (isLocal && tbase > qwmax) continue;  // fully-masked sub-tile

        // ---- QK^T (swapped): S^T[key][q], K from LDS ----
        float sv[32];
        __builtin_amdgcn_s_setprio(1);
#pragma unroll
        for (int kb = 0; kb < 2; kb++) {
          const u16* krow = &kT[p][sub * 64 + kb * 32 + l31][hi * 8];
          bf16x8 k0 = *(const bf16x8*)(krow);
          bf16x8 k1 = *(const bf16x8*)(krow + 16);
          bf16x8 k2 = *(const bf16x8*)(krow + 32);
          bf16x8 k3 = *(const bf16x8*)(krow + 48);
          f32x16 z = {};
          z = __builtin_amdgcn_mfma_f32_32x32x16_bf16(k0, qf[0], z, 0, 0, 0);
          z = __builtin_amdgcn_mfma_f32_32x32x16_bf16(k1, qf[1], z, 0, 0, 0);
          z = __builtin_amdgcn_mfma_f32_32x32x16_bf16(k2, qf[2], z, 0, 0, 0);
          z = __builtin_amdgcn_mfma_f32_32x32x16_bf16(k3, qf[3], z, 0, 0, 0);
#pragma unroll
          for (int r = 0; r < 16; r++) sv[kb * 16 + r] = z[r];
        }
        __builtin_amdgcn_s_setprio(0);

        // ---- causal mask (scale already folded into Q) ----
        if (isLocal) {
          const int lim = qrow - tbase;
          if (lim < 63) {
#pragma unroll
            for (int kb = 0; kb < 2; kb++)
#pragma unroll
              for (int r = 0; r < 16; r++) {
                int crow = kb * 32 + (r & 3) + 8 * (r >> 2) + 4 * hi;
                if (crow > lim) sv[kb * 16 + r] = -3.0e38f;
              }
          }
        } else {
#pragma unroll
          for (int kb = 0; kb < 2; kb++)
#pragma unroll
            for (int r = 0; r < 16; r++) {
              int kpos = gposLds[p][sub * 64 + kb * 32 + (r & 3) + 8 * (r >> 2) + 4 * hi];
              if (kpos > qrow) sv[kb * 16 + r] = -3.0e38f;
            }
        }

        // ---- lane-local online softmax with defer-max ----
        float m0 = sv[0], m1 = sv[1], m2 = sv[2], m3 = sv[3];
#pragma unroll
        for (int i = 4; i < 32; i += 4) {
          m0 = fmaxf(m0, sv[i]);     m1 = fmaxf(m1, sv[i + 1]);
          m2 = fmaxf(m2, sv[i + 2]); m3 = fmaxf(m3, sv[i + 3]);
        }
        float vmax = fmaxf(fmaxf(m0, m1), fmaxf(m2, m3));
        vmax = fmaxf(vmax, __shfl_xor(vmax, 32));
        if (__any(vmax > mr + 11.0f)) {
          float mn = fmaxf(mr, vmax);
          float al = exp2f(mr - mn);
          lr *= al;
          mr = mn;
#pragma unroll
          for (int i = 0; i < 16; i++) { acc0[i] *= al; acc1[i] *= al; }
        }
        float s0 = 0.f, s1 = 0.f, s2 = 0.f, s3 = 0.f;
#pragma unroll
        for (int i = 0; i < 32; i += 4) {
          float p0 = exp2f(sv[i] - mr),     p1 = exp2f(sv[i + 1] - mr);
          float p2 = exp2f(sv[i + 2] - mr), p3 = exp2f(sv[i + 3] - mr);
          sv[i] = p0; sv[i + 1] = p1; sv[i + 2] = p2; sv[i + 3] = p3;
          s0 += p0; s1 += p1; s2 += p2; s3 += p3;
        }
        float ps = (s0 + s1) + (s2 + s3);
        ps += __shfl_xor(ps, 32);
        lr += ps;

        // ---- build P B-fragments in-register (cvt_pk + half-swap with lane^32) ----
        bf16x8 pf[4];
#pragma unroll
        for (int q4 = 0; q4 < 4; q4++) {
          int b = q4 * 8;
          uint32_t w0 = cvtpk(sv[b + 0], sv[b + 1]);
          uint32_t w1 = cvtpk(sv[b + 2], sv[b + 3]);
          uint32_t w2 = cvtpk(sv[b + 4], sv[b + 5]);
          uint32_t w3 = cvtpk(sv[b + 6], sv[b + 7]);
          uint32_t w0s = __shfl_xor((int)w0, 32), w2s = __shfl_xor((int)w2, 32);
          uint32_t w1s = __shfl_xor((int)w1, 32), w3s = __shfl_xor((int)w3, 32);
          union { uint32_t w[4]; bf16x8 v; } u;
          u.w[0] = hi ? w2s : w0;
          u.w[1] = hi ? w3s : w1;
          u.w[2] = hi ? w2 : w0s;
          u.w[3] = hi ? w3 : w1s;
          pf[q4] = u.v;
        }

        // ---- PV: O^T[d][q] = mfma(V^T, P) ----
        __builtin_amdgcn_s_setprio(1);
#pragma unroll
        for (int dblk = 0; dblk < 2; dblk++) {
          const int swz = (dblk * 2 + (l31 >> 4)) << 4;
          const u16* vrow = &vT[p][dblk * 32 + l31][sub * 64];
          f32x16 a = dblk ? acc1 : acc0;
#pragma unroll
          for (int ksg = 0; ksg < 4; ksg++) {
            bf16x8 vf = *(const bf16x8*)(vrow + ((ksg * 16 + hi * 8) ^ swz));
            a = __builtin_amdgcn_mfma_f32_32x32x16_bf16(vf, pf[ksg], a, 0, 0, 0);
          }
          if (dblk) acc1 = a; else acc0 = a;
        }
        __builtin_amdgcn_s_setprio(0);
      }
    }

    // ---- normalize (lane-local) + store O for this supertile ----
    float inv = 1.0f / lr;
#pragma unroll
    for (int dblk = 0; dblk < 2; dblk++) {
      f32x16 a = dblk ? acc1 : acc0;
#pragma unroll
      for (int g = 0; g < 4; g++) {
        uint64_t pk = (uint64_t)f2bf(a[g * 4 + 0] * inv)
                    | ((uint64_t)f2bf(a[g * 4 + 1] * inv) << 16)
                    | ((uint64_t)f2bf(a[g * 4 + 2] * inv) << 32)
                    | ((uint64_t)f2bf(a[g * 4 + 3] * inv) << 48);
        *(uint64_t*)(o + (size_t)qrow * DIM + hoff + dblk * 32 + g * 8 + 4 * hi) = pk;
      }
    }
  }
}

// ---------------- launch ----------------
extern "C" void kernel_launch(void* const* d_in, const int* in_sizes, int n_in,
                              void* d_out, int out_size, void* d_ws, size_t ws_size,
                              hipStream_t stream) {
  const float* x  = (const float*)d_in[0];
  const float* nw = (const float*)d_in[1];
  const float* wq = (const float*)d_in[2];
  const float* wk = (const float*)d_in[3];
  const float* wv = (const float*)d_in[4];
  const float* wo = (const float*)d_in[5];
  const float* sw = (const float*)d_in[6];
  const float* sb = (const float*)d_in[7];
  float* out = (float*)d_out;

  char* ws = (char*)d_ws;
  size_t off = 0;
  auto alloc = [&](size_t b) {
    char* p = ws + off;
    off = (off + b + 255) & ~(size_t)255;
    return p;
  };
  u16*   h      = (u16*)alloc((size_t)S_LEN * DIM * 2);
  u16*   wqkvT  = (u16*)alloc((size_t)3 * DIM * DIM * 2);
  u16*   woutT  = (u16*)alloc((size_t)DIM * DIM * 2);
  u16*   qkv    = (u16*)alloc((size_t)S_LEN * 3 * DIM * 2);
  u16*   obuf   = (u16*)alloc((size_t)S_LEN * DIM * 2);
  float* scores = (float*)alloc((size_t)S_LEN * 4);
  int*   cnt    = (int*)alloc((size_t)S_LEN * 4);
  int*   gidx   = (int*)alloc((size_t)GTOK * 4);
  u16*   kgbuf  = (u16*)alloc((size_t)GTOK * DIM * 2);
  u16*   vgbuf  = (u16*)alloc((size_t)GTOK * DIM * 2);

  transpose_w_kernel<<<dim3(32, 32, 4), dim3(32, 8), 0, stream>>>(wq, wk, wv, wo, wqkvT, woutT);
  rmsnorm_score_kernel<<<dim3(S_LEN), dim3(256), 0, stream>>>(x, nw, sw, sb, h, scores, cnt);
  topk_count_kernel<<<dim3(32, 8), dim3(256), 0, stream>>>(scores, cnt);
  topk_scatter_kernel<<<dim3(S_LEN / 256), dim3(256), 0, stream>>>(cnt, gidx);
  gemm256_kernel<0><<<dim3(32, 24), dim3(512), 0, stream>>>(h, wqkvT, qkv, nullptr, nullptr,
                                                            S_LEN, 3 * DIM, DIM);
  gather_kernel<<<dim3(GTOK), dim3(128), 0, stream>>>(qkv, gidx, kgbuf, vgbuf);
  attn_kernel<<<dim3(16, NH), dim3(512), 0, stream>>>(qkv, kgbuf, vgbuf, gidx, obuf);
  gemm256_kernel<1><<<dim3(32, 8), dim3(512), 0, stream>>>(obuf, woutT, nullptr, out, x,
                                                           S_LEN, DIM, DIM);
}